// Round 9
// baseline (585.264 us; speedup 1.0000x reference)
//
#include <hip/hip_runtime.h>
#include <stdint.h>

// ---------------------------------------------------------------------------
// Problem constants (fixed by setup_inputs)
// b=32, n=1024, dim=512, ic=512, cc=256, nh=8, ag=49, hd=64, H=W=c_H=c_W=32
// ---------------------------------------------------------------------------

typedef __attribute__((ext_vector_type(8)))  short          bf16x8;
typedef __attribute__((ext_vector_type(4)))  float          f32x4;
typedef __attribute__((ext_vector_type(4)))  unsigned short u16x4;

__device__ __forceinline__ float bf2f(unsigned short u) {
    union { unsigned int i; float f; } x; x.i = ((unsigned int)u) << 16; return x.f;
}
__device__ __forceinline__ unsigned short f2bf(float f) {
    union { float f; unsigned int i; } x; x.f = f;
    unsigned int i = x.i;
    i += 0x7FFFu + ((i >> 16) & 1u);   // RNE
    return (unsigned short)(i >> 16);
}

// ---------------------------------------------------------------------------
// Bias precompute helpers (bilinear 7->32, clamp edges)
// ---------------------------------------------------------------------------
__device__ __forceinline__ void bilin_coef(int i, int& i0, int& i1, float& f) {
    float pos = (i + 0.5f) * (7.0f / 32.0f) - 0.5f;
    float fl = floorf(pos);
    i0 = (int)fl; f = pos - fl;
    if (i0 < 0)       { i0 = 0; i1 = 0; f = 0.f; }
    else if (i0 >= 6) { i0 = 6; i1 = 6; f = 0.f; }
    else              { i1 = i0 + 1; }
}
__device__ __forceinline__ float bilin7(const float* __restrict__ s, int y, int x) {
    int y0,y1,x0,x1; float fy,fx;
    bilin_coef(y, y0, y1, fy); bilin_coef(x, x0, x1, fx);
    return (1.f-fy)*((1.f-fx)*s[y0*7+x0] + fx*s[y0*7+x1])
         +      fy *((1.f-fx)*s[y1*7+x0] + fx*s[y1*7+x1]);
}

// ---------------------------------------------------------------------------
// Merged prep kernel (r9: + x->bf16 cvt; 6-in-1, one launch).
// Ranges: [0,4194304) x cvt x4-vectorized | then wqkvt 786432 | projwt 262144
//         | bias1 401408 | bias2 401408 | convwb 3538944.
// Total threads 9584640 -> 37440 blocks.
// ---------------------------------------------------------------------------
__global__ void prep_all_kernel(const float* __restrict__ x,
                                const float* __restrict__ Wq,
                                const float* __restrict__ Wkv,
                                const float* __restrict__ Wproj,
                                const float* __restrict__ conv_w,
                                const float* __restrict__ an, const float* __restrict__ na,
                                const float* __restrict__ ah, const float* __restrict__ aw,
                                const float* __restrict__ ha, const float* __restrict__ wa,
                                unsigned short* __restrict__ xb,
                                unsigned short* __restrict__ wqkvt,
                                unsigned short* __restrict__ projwt,
                                float* __restrict__ bias1,
                                float* __restrict__ bias2,
                                unsigned short* __restrict__ convwb) {
    int idx = blockIdx.x * 256 + threadIdx.x;
    if (idx < 4194304) {
        const int i = idx * 4;
        const f32x4 v = *(const f32x4*)(x + i);
        u16x4 o; o[0]=f2bf(v[0]); o[1]=f2bf(v[1]); o[2]=f2bf(v[2]); o[3]=f2bf(v[3]);
        *(u16x4*)(xb + i) = o;
        return;
    }
    idx -= 4194304;
    if (idx < 786432) {
        const int nn = idx >> 9, kk = idx & 511;
        float v = (nn < 512) ? Wq[kk*512 + nn] : Wkv[kk*1024 + (nn - 512)];
        wqkvt[idx] = f2bf(v);
        return;
    }
    idx -= 786432;
    if (idx < 262144) {
        const int nn = idx >> 9, kk = idx & 511;
        projwt[idx] = f2bf(Wproj[kk*512 + nn]);
        return;
    }
    idx -= 262144;
    if (idx < 8*49*1024) {
        const int nn = idx & 1023;
        const int a  = (idx >> 10) % 49;
        const int h  = idx / (49*1024);
        const int y = nn >> 5, xq = nn & 31;
        float v = bilin7(an + (h*49 + a)*49, y, xq)
                + ah[(h*49 + a)*32 + y] + aw[(h*49 + a)*32 + xq];
        bias1[idx] = v;
        return;
    }
    idx -= 8*49*1024;
    if (idx < 8*1024*49) {
        const int a  = idx % 49;
        const int nn = (idx / 49) & 1023;
        const int h  = idx / (49*1024);
        const int y = nn >> 5, xq = nn & 31;
        float v = bilin7(na + (h*49 + a)*49, y, xq)
                + ha[h*1568 + y*49 + a] + wa[h*1568 + xq*49 + a];
        bias2[idx] = v;
        return;
    }
    idx -= 8*1024*49;
    if (idx < 3538944) convwb[idx] = f2bf(conv_w[idx]);
}

// ---------------------------------------------------------------------------
// Fused adaptive-pool(32x32->7x7) + im2col (r9).
// Grid (32 b x 16 cgroups of 48 ch), 256 thr. Per block: pool its 49x48
// tile into LDS once (same window math as before), then emit all im2col
// slots for those channels with coalesced bf16 writes (border zeros inline).
// Eliminates the pooled[] round-trip and the 42336-block im2col kernel.
// i2c layout unchanged: [(b*49 + p*7+q)*6912 + ci*9 + dy*3+dx].
// ---------------------------------------------------------------------------
__launch_bounds__(256)
__global__ void pool_i2c_kernel(const unsigned short* __restrict__ qkv,
                                const float* __restrict__ context,
                                unsigned short* __restrict__ i2c) {
    __shared__ float ps[49*48];
    const int b  = blockIdx.x >> 4;
    const int cg = blockIdx.x & 15;
    const int c0 = cg * 48;
    const int tid = threadIdx.x;

    for (int v = tid; v < 49*48; v += 256) {
        const int a  = v / 48, cl = v - a*48;
        const int c  = c0 + cl;
        const int p  = a / 7, q = a - p*7;
        const int ys = p*32/7, ye = (p*32 + 38)/7;
        const int xs = q*32/7, xe = (q*32 + 38)/7;
        float s = 0.f;
        if (c < 512) {
            for (int y = ys; y < ye; ++y)
                for (int xx = xs; xx < xe; ++xx)
                    s += bf2f(qkv[(size_t)(b*1024 + y*32 + xx)*1536 + c]);
        } else {
            for (int y = ys; y < ye; ++y)
                for (int xx = xs; xx < xe; ++xx)
                    s += context[(size_t)(b*1024 + y*32 + xx)*256 + (c - 512)];
        }
        ps[v] = s / (float)((ye - ys)*(xe - xs));
    }
    __syncthreads();

    // 49 patches x 48 ch x 9 taps = 21168 writes; consecutive o -> consecutive
    // global address (r fastest, then ci) = coalesced.
    for (int o = tid; o < 49*48*9; o += 256) {
        const int spq = o / 432;
        const int cc  = o - spq*432;
        const int cl  = cc / 9, r = cc - cl*9;
        const int dy  = r / 3,  dx = r - dy*3;
        const int p   = spq / 7, q = spq - p*7;
        const int yy  = p + dy - 1, xx = q + dx - 1;
        float v = 0.f;
        if (yy >= 0 && yy < 7 && xx >= 0 && xx < 7)
            v = ps[(yy*7 + xx)*48 + cl];
        i2c[(size_t)(b*49 + spq)*6912 + (c0 + cl)*9 + r] = f2bf(v);
    }
}

// ---------------------------------------------------------------------------
// NT bf16 MFMA GEMM (m97 structure) — conv split-K GEMM. MODE 3 only.
// ---------------------------------------------------------------------------
template <int MODE>
__launch_bounds__(256)
__global__ void gemm_nt(const unsigned short* __restrict__ A,
                        const unsigned short* __restrict__ Bt,
                        void* __restrict__ C,
                        const float* __restrict__ bias,
                        int K, int ldc, int kspan) {
    __shared__ __align__(16) unsigned char smem_raw[32768];
    unsigned short* As = (unsigned short*)smem_raw;           // [128][64] bf16
    unsigned short* Bs = (unsigned short*)(smem_raw + 16384); // [128][64] bf16

    // ---- T1 swizzle ----
    const int gx  = gridDim.x;
    const int gxy = gridDim.x * gridDim.y;
    const int nwg = gxy * gridDim.z;
    const int L   = (blockIdx.z * gridDim.y + blockIdx.y) * gx + blockIdx.x;
    const int qq  = nwg >> 3, rr = nwg & 7;
    const int xcd = L & 7,   ii = L >> 3;
    const int W   = (xcd < rr ? xcd * (qq + 1) : rr * (qq + 1) + (xcd - rr) * qq) + ii;
    const int bz  = W / gxy;
    const int rem = W - bz * gxy;
    const int by  = rem / gx;
    const int bx  = rem - by * gx;

    const int tid  = threadIdx.x;
    const int wid  = tid >> 6;
    const int lane = tid & 63;
    const int m0 = by * 128;
    const int n0 = bx * 128;
    const int wm = (wid >> 1) * 64;
    const int wn = (wid & 1) * 64;
    const int lrow = lane & 15;
    const int quad = lane >> 4;
    const int srow = lane >> 3;
    const int scol = ((lane & 7) ^ srow) * 8;

    f32x4 acc[4][4];
#pragma unroll
    for (int i = 0; i < 4; ++i)
#pragma unroll
        for (int j = 0; j < 4; ++j) acc[i][j] = (f32x4){0.f,0.f,0.f,0.f};

    const int kz0 = bz * kspan;
    const int kz1 = min(K, kz0 + kspan);
    for (int k0 = kz0; k0 < kz1; k0 += 64) {
        __syncthreads();
#pragma unroll
        for (int i = 0; i < 4; ++i) {
            const int chunk = wid*4 + i;
            const int row = chunk*8 + srow;
            __builtin_amdgcn_global_load_lds(
                (const __attribute__((address_space(1))) void*)(A + (size_t)(m0 + row)*K + k0 + scol),
                (__attribute__((address_space(3))) void*)(As + chunk*512), 16, 0, 0);
            __builtin_amdgcn_global_load_lds(
                (const __attribute__((address_space(1))) void*)(Bt + (size_t)(n0 + row)*K + k0 + scol),
                (__attribute__((address_space(3))) void*)(Bs + chunk*512), 16, 0, 0);
        }
        __syncthreads();
#pragma unroll
        for (int kk = 0; kk < 2; ++kk) {
            bf16x8 af[4], bfr[4];
#pragma unroll
            for (int mt = 0; mt < 4; ++mt) {
                const int row = wm + mt*16 + lrow;
                const int u = (kk*4 + quad) ^ (row & 7);
                af[mt] = *(const bf16x8*)(As + row*64 + u*8);
            }
#pragma unroll
            for (int nt = 0; nt < 4; ++nt) {
                const int row = wn + nt*16 + lrow;
                const int u = (kk*4 + quad) ^ (row & 7);
                bfr[nt] = *(const bf16x8*)(Bs + row*64 + u*8);
            }
#pragma unroll
            for (int mt = 0; mt < 4; ++mt)
#pragma unroll
                for (int nt = 0; nt < 4; ++nt)
                    acc[mt][nt] = __builtin_amdgcn_mfma_f32_16x16x32_bf16(
                        af[mt], bfr[nt], acc[mt][nt], 0, 0, 0);
        }
    }

    // ---- LDS-staged epilogue (f32 modes) ----
    __syncthreads();
    {
        float* Cf = (float*)smem_raw;                     // [64][128] f32, XOR-swz
#pragma unroll
        for (int half = 0; half < 2; ++half) {
            if ((wid >> 1) == half) {
#pragma unroll
                for (int mt = 0; mt < 4; ++mt)
#pragma unroll
                    for (int nt = 0; nt < 4; ++nt)
#pragma unroll
                        for (int r = 0; r < 4; ++r) {
                            const int mr = mt*16 + quad*4 + r;
                            const int n  = wn + nt*16 + lrow;
                            Cf[mr*128 + (n ^ ((mr & 7) << 2))] = acc[mt][nt][r];
                        }
            }
            __syncthreads();
#pragma unroll
            for (int it = 0; it < 8; ++it) {
                const int idx = it*256 + tid;
                const int row = idx >> 5, c4 = idx & 31;
                const int m = m0 + half*64 + row;
                f32x4 v = *(const f32x4*)(Cf + row*128 + ((c4*4) ^ ((row & 7) << 2)));
                if (MODE == 0) {
                    const f32x4 bb = *(const f32x4*)(bias + n0 + c4*4);
                    v[0]+=bb[0]; v[1]+=bb[1]; v[2]+=bb[2]; v[3]+=bb[3];
                    *(f32x4*)((float*)C + (size_t)m*ldc + n0 + c4*4) = v;
                } else {
                    if (m < 1568)
                        *(f32x4*)((float*)C + ((size_t)bz*1568 + m)*512 + n0 + c4*4) = v;
                }
            }
            __syncthreads();
        }
    }
}

// ---------------------------------------------------------------------------
// 256x256 8-phase pipelined NT bf16 GEMM (T3+T4+T5+T2, verified r5).
// MODE 0: f32 C + bias (proj)    MODE 1: bf16 C (qkv)
// ---------------------------------------------------------------------------
#define STAGE_A(DST, T, Q) do {                                                             \
    _Pragma("unroll")                                                                       \
    for (int l_ = 0; l_ < 2; ++l_) {                                                        \
        const int rb_ = l_*128 + (Q)*64 + wid*8;                                            \
        __builtin_amdgcn_global_load_lds(                                                   \
            (const __attribute__((address_space(1))) void*)                                 \
                (Ag + (size_t)(m0 + rb_ + lr8)*K + (T)*64 + scl),                           \
            (__attribute__((address_space(3))) void*)((DST) + rb_*64), 16, 0, 0);           \
    }                                                                                       \
} while (0)

#define STAGE_B(DST, T, NH) do {                                                            \
    _Pragma("unroll")                                                                       \
    for (int l_ = 0; l_ < 2; ++l_) {                                                        \
        const int w8_ = wid*8;                                                              \
        const int rb_ = l_*128 + ((w8_ >> 5) << 6) + (NH)*32 + (w8_ & 31);                  \
        __builtin_amdgcn_global_load_lds(                                                   \
            (const __attribute__((address_space(1))) void*)                                 \
                (Btg + (size_t)(n0 + rb_ + lr8)*K + (T)*64 + scl),                          \
            (__attribute__((address_space(3))) void*)((DST) + rb_*64), 16, 0, 0);           \
    }                                                                                       \
} while (0)

#define LOAD_A(MH, SRC) do {                                                                \
    _Pragma("unroll")                                                                       \
    for (int m4_ = 0; m4_ < 4; ++m4_)                                                       \
    _Pragma("unroll")                                                                       \
    for (int kk_ = 0; kk_ < 2; ++kk_)                                                       \
        aF[m4_][kk_] = *(const bf16x8*)                                                     \
            ((SRC) + (wr*128 + ((MH)*4 + m4_)*16 + l15)*64                                  \
                   + (((kk_*4 + quad) ^ sw7) * 8));                                         \
} while (0)

#define LOAD_B(NH, DSTF, SRC) do {                                                          \
    _Pragma("unroll")                                                                       \
    for (int n2_ = 0; n2_ < 2; ++n2_)                                                       \
    _Pragma("unroll")                                                                       \
    for (int kk_ = 0; kk_ < 2; ++kk_)                                                       \
        DSTF[n2_][kk_] = *(const bf16x8*)                                                   \
            ((SRC) + (wc*64 + ((NH)*2 + n2_)*16 + l15)*64                                   \
                   + (((kk_*4 + quad) ^ sw7) * 8));                                         \
} while (0)

#define MFMA_PHASE(MH, NH, BF) do {                                                         \
    __builtin_amdgcn_s_barrier();                                                           \
    asm volatile("s_waitcnt lgkmcnt(0)");                                                   \
    __builtin_amdgcn_sched_barrier(0);                                                      \
    __builtin_amdgcn_s_setprio(1);                                                          \
    _Pragma("unroll")                                                                       \
    for (int kk_ = 0; kk_ < 2; ++kk_)                                                       \
    _Pragma("unroll")                                                                       \
    for (int m4_ = 0; m4_ < 4; ++m4_)                                                       \
    _Pragma("unroll")                                                                       \
    for (int n2_ = 0; n2_ < 2; ++n2_)                                                       \
        acc[(MH)*4 + m4_][(NH)*2 + n2_] = __builtin_amdgcn_mfma_f32_16x16x32_bf16(          \
            aF[m4_][kk_], BF[n2_][kk_], acc[(MH)*4 + m4_][(NH)*2 + n2_], 0, 0, 0);          \
    __builtin_amdgcn_s_setprio(0);                                                          \
    __builtin_amdgcn_sched_barrier(0);                                                      \
} while (0)

template <int MODE>
__launch_bounds__(512, 1)
__global__ void gemm_nt8(const unsigned short* __restrict__ Ag,
                         const unsigned short* __restrict__ Btg,
                         void* __restrict__ C,
                         const float* __restrict__ bias,
                         int K, int ldc) {
    __shared__ unsigned short AsB[2][16384];
    __shared__ unsigned short BsB[2][16384];

    const int gx  = gridDim.x;
    const int nwg = gx * gridDim.y;
    const int L   = blockIdx.y * gx + blockIdx.x;
    const int qq  = nwg >> 3, rr = nwg & 7;
    const int xcd = L & 7,   ii = L >> 3;
    const int W   = (xcd < rr ? xcd * (qq + 1) : rr * (qq + 1) + (xcd - rr) * qq) + ii;
    const int bx  = W % gx, by = W / gx;
    const int m0  = by * 256, n0 = bx * 256;

    const int tid  = threadIdx.x;
    const int wid  = tid >> 6, lane = tid & 63;
    const int wr   = wid >> 2, wc = wid & 3;
    const int l15  = lane & 15, quad = lane >> 4;
    const int lr8  = lane >> 3;
    const int scl  = ((lane & 7) ^ lr8) * 8;
    const int sw7  = l15 & 7;
    const int KT   = K >> 6;

    unsigned short *Acur = &AsB[0][0], *Anxt = &AsB[1][0];
    unsigned short *Bcur = &BsB[0][0], *Bnxt = &BsB[1][0];

    f32x4 acc[8][4];
#pragma unroll
    for (int i = 0; i < 8; ++i)
#pragma unroll
        for (int j = 0; j < 4; ++j) acc[i][j] = (f32x4){0.f,0.f,0.f,0.f};

    bf16x8 aF[4][2], bF0[2][2], bF1[2][2];

    STAGE_A(Acur, 0, 0); STAGE_B(Bcur, 0, 1); STAGE_A(Acur, 0, 1); STAGE_B(Bcur, 0, 0);
    STAGE_A(Anxt, 1, 0); STAGE_B(Bnxt, 1, 1); STAGE_A(Anxt, 1, 1);
    asm volatile("s_waitcnt vmcnt(6)");
    __builtin_amdgcn_s_barrier();

    for (int t = 0; t < KT; ++t) {
        LOAD_B(0, bF0, Bcur);
        LOAD_A(0, Acur);
        if (t + 1 < KT) STAGE_B(Bnxt, t + 1, 0);
        MFMA_PHASE(0, 0, bF0);
        __builtin_amdgcn_s_barrier();

        LOAD_B(1, bF1, Bcur);
        if (t + 2 < KT) STAGE_A(Acur, t + 2, 0);
        MFMA_PHASE(0, 1, bF1);
        __builtin_amdgcn_s_barrier();

        LOAD_A(1, Acur);
        if (t + 2 < KT) STAGE_B(Bcur, t + 2, 1);
        MFMA_PHASE(1, 1, bF1);
        __builtin_amdgcn_s_barrier();

        LOAD_B(0, bF0, Bcur);
        if (t + 2 < KT) STAGE_A(Acur, t + 2, 1);
        MFMA_PHASE(1, 0, bF0);
        if (t + 2 < KT) asm volatile("s_waitcnt vmcnt(6)");
        else            asm volatile("s_waitcnt vmcnt(0)");
        __builtin_amdgcn_s_barrier();

        unsigned short* tmp;
        tmp = Acur; Acur = Anxt; Anxt = tmp;
        tmp = Bcur; Bcur = Bnxt; Bnxt = tmp;
    }

    if (MODE == 1) {
#pragma unroll
        for (int mt = 0; mt < 8; ++mt)
#pragma unroll
            for (int nt = 0; nt < 4; ++nt)
#pragma unroll
                for (int r = 0; r < 4; ++r) {
                    const int m = m0 + wr*128 + mt*16 + quad*4 + r;
                    const int n = n0 + wc*64  + nt*16 + l15;
                    ((unsigned short*)C)[(size_t)m*ldc + n] = f2bf(acc[mt][nt][r]);
                }
    } else {
        float bv[4];
#pragma unroll
        for (int nt = 0; nt < 4; ++nt) bv[nt] = bias[n0 + wc*64 + nt*16 + l15];
#pragma unroll
        for (int mt = 0; mt < 8; ++mt)
#pragma unroll
            for (int nt = 0; nt < 4; ++nt)
#pragma unroll
                for (int r = 0; r < 4; ++r) {
                    const int m = m0 + wr*128 + mt*16 + quad*4 + r;
                    const int n = n0 + wc*64  + nt*16 + l15;
                    ((float*)C)[(size_t)m*ldc + n] = acc[mt][nt][r] + bv[nt];
                }
    }
}

#undef STAGE_A
#undef STAGE_B
#undef LOAD_A
#undef LOAD_B
#undef MFMA_PHASE

// Sum 9 split-K partials, add conv bias, emit bf16 a_t.
__global__ void convred_kernel(const float* __restrict__ part,
                               const float* __restrict__ bias,
                               unsigned short* __restrict__ at_bf) {
    const int idx = blockIdx.x * 256 + threadIdx.x;   // over 1568*128
    if (idx >= 1568*128) return;
    const int m  = idx >> 7;
    const int n4 = (idx & 127) * 4;
    f32x4 s = *(const f32x4*)&part[(size_t)m*512 + n4];
#pragma unroll
    for (int kz = 1; kz < 9; ++kz) {
        const f32x4 p = *(const f32x4*)&part[((size_t)kz*1568 + m)*512 + n4];
        s[0]+=p[0]; s[1]+=p[1]; s[2]+=p[2]; s[3]+=p[3];
    }
    u16x4 o;
    o[0] = f2bf(s[0] + bias[n4+0]);
    o[1] = f2bf(s[1] + bias[n4+1]);
    o[2] = f2bf(s[2] + bias[n4+2]);
    o[3] = f2bf(s[3] + bias[n4+3]);
    *(u16x4*)&at_bf[(size_t)m*512 + n4] = o;
}

// ---------------------------------------------------------------------------
// MFMA agent attention. Grid (256 bh, 4 slices), 256 thr (4 waves).
// ---------------------------------------------------------------------------
__launch_bounds__(256)
__global__ void agent_attn_mfma_kernel(const unsigned short* __restrict__ qkv,
                                       const unsigned short* __restrict__ at_bf,
                                       const float* __restrict__ bias1,
                                       float* __restrict__ pn,
                                       float* __restrict__ pd) {
    const int bh = blockIdx.x;
    const int b = bh >> 3, h = bh & 7;
    const int sl = blockIdx.y;
    __shared__ unsigned short at_s[64*72];
    __shared__ __align__(16) unsigned char smem[4*64*72*2 + 4*64*64*2];
    unsigned short* P_s = (unsigned short*)smem;
    unsigned short* V_s = (unsigned short*)(smem + 36864);
    float* red  = (float*)smem;
    float* dred = (float*)(smem + 65536);
    const int tid  = threadIdx.x;
    const int wid  = tid >> 6, lane = tid & 63;
    const int l15  = lane & 15, quad = lane >> 4;
    const int j0   = sl*256 + wid*64;

    for (int i = tid; i < 64*72; i += 256) at_s[i] = 0;
    __syncthreads();
    for (int i = tid; i < 49*16; i += 256) {
        const int a = i >> 4, dq = (i & 15) * 4;
        *(u16x4*)&at_s[a*72 + dq] = *(const u16x4*)&at_bf[(size_t)(b*49 + a)*512 + h*64 + dq];
    }
#pragma unroll
    for (int i = 0; i < 8; ++i) {
        __builtin_amdgcn_global_load_lds(
            (const __attribute__((address_space(1))) void*)
                (qkv + (size_t)(b*1024 + j0 + i*8 + (lane>>3))*1536 + 1024 + h*64 + (lane&7)*8),
            (__attribute__((address_space(3))) void*)(V_s + wid*4096 + i*512), 16, 0, 0);
    }
    bf16x8 kfr[4][2];
#pragma unroll
    for (int nt = 0; nt < 4; ++nt)
#pragma unroll
        for (int kf = 0; kf < 2; ++kf)
            kfr[nt][kf] = *(const bf16x8*)
                (qkv + (size_t)(b*1024 + j0 + nt*16 + l15)*1536 + 512 + h*64 + kf*32 + quad*8);
    __syncthreads();

    bf16x8 af[4][2];
#pragma unroll
    for (int mt = 0; mt < 4; ++mt)
#pragma unroll
        for (int kf = 0; kf < 2; ++kf)
            af[mt][kf] = *(const bf16x8*)(at_s + (mt*16 + l15)*72 + kf*32 + quad*8);

    f32x4 acc[4][4];
#pragma unroll
    for (int i = 0; i < 4; ++i)
#pragma unroll
        for (int j = 0; j < 4; ++j) acc[i][j] = (f32x4){0.f,0.f,0.f,0.f};
#pragma unroll
    for (int kf = 0; kf < 2; ++kf)
#pragma unroll
        for (int mt = 0; mt < 4; ++mt)
#pragma unroll
            for (int nt = 0; nt < 4; ++nt)
                acc[mt][nt] = __builtin_amdgcn_mfma_f32_16x16x32_bf16(
                    af[mt][kf], kfr[nt][kf], acc[mt][nt], 0, 0, 0);

    float denp[4][4];
#pragma unroll
    for (int mt = 0; mt < 4; ++mt)
#pragma unroll
        for (int r = 0; r < 4; ++r) denp[mt][r] = 0.f;
#pragma unroll
    for (int mt = 0; mt < 4; ++mt) {
#pragma unroll
        for (int nt = 0; nt < 4; ++nt) {
#pragma unroll
            for (int r = 0; r < 4; ++r) {
                const int a  = mt*16 + quad*4 + r;
                const int ab = (a < 49) ? a : 48;
                const int jj = j0 + nt*16 + l15;
                const float e = __expf(fmaf(0.125f, acc[mt][nt][r],
                                            bias1[(h*49 + ab)*1024 + jj]));
                denp[mt][r] += e;
                P_s[wid*4608 + a*72 + nt*16 + l15] = f2bf(e);
            }
        }
    }
    __syncthreads();

    f32x4 out[4][4];
#pragma unroll
    for (int i = 0; i < 4; ++i)
#pragma unroll
        for (int j = 0; j < 4; ++j) out[i][j] = (f32x4){0.f,0.f,0.f,0.f};
#pragma unroll
    for (int kf = 0; kf < 2; ++kf) {
        bf16x8 va[4];
#pragma unroll
        for (int mt = 0; mt < 4; ++mt) {
            union { bf16x8 v; unsigned short s[8]; } u;
#pragma unroll
            for (int t = 0; t < 8; ++t)
                u.s[t] = V_s[wid*4096 + (kf*32 + quad*8 + t)*64 + mt*16 + l15];
            va[mt] = u.v;
        }
#pragma unroll
        for (int nt = 0; nt < 4; ++nt) {
            const bf16x8 pb = *(const bf16x8*)(P_s + wid*4608 + (nt*16 + l15)*72 + kf*32 + quad*8);
#pragma unroll
            for (int mt = 0; mt < 4; ++mt)
                out[mt][nt] = __builtin_amdgcn_mfma_f32_16x16x32_bf16(
                    va[mt], pb, out[mt][nt], 0, 0, 0);
        }
    }

#pragma unroll
    for (int mt = 0; mt < 4; ++mt) {
#pragma unroll
        for (int r = 0; r < 4; ++r) {
            float v = denp[mt][r];
            v += __shfl_xor(v, 1);
            v += __shfl_xor(v, 2);
            v += __shfl_xor(v, 4);
            v += __shfl_xor(v, 8);
            denp[mt][r] = v;
        }
    }

    __syncthreads();
#pragma unroll
    for (int nt = 0; nt < 4; ++nt) {
        const int a = nt*16 + l15;
#pragma unroll
        for (int mt = 0; mt < 4; ++mt)
            *(f32x4*)&red[wid*4096 + a*64 + mt*16 + quad*4] = out[mt][nt];
    }
    if (l15 == 0) {
#pragma unroll
        for (int mt = 0; mt < 4; ++mt)
#pragma unroll
            for (int r = 0; r < 4; ++r)
                dred[wid*64 + mt*16 + quad*4 + r] = denp[mt][r];
    }
    __syncthreads();
    for (int i = tid; i < 4096; i += 256) {
        const float s = red[i] + red[4096 + i] + red[8192 + i] + red[12288 + i];
        pn[((size_t)bh*4 + sl)*4096 + i] = s;
    }
    if (tid < 64) {
        const float s = dred[tid] + dred[64 + tid] + dred[128 + tid] + dred[192 + tid];
        pd[((size_t)bh*4 + sl)*64 + tid] = s;
    }
}

// Combine 4 j-slice partials; emit bf16 agent_v transposed [bh][d][a-pad-64].
__global__ void agent_combine_kernel(const float* __restrict__ pn,
                                     const float* __restrict__ pd,
                                     unsigned short* __restrict__ avT) {
    const int idx = blockIdx.x * 256 + threadIdx.x;
    if (idx >= 256*4096) return;
    const int bh = idx >> 12;
    const int i  = idx & 4095;
    const int a = i >> 6, d = i & 63;
    float num = 0.f, den = 0.f;
#pragma unroll
    for (int s = 0; s < 4; ++s) {
        num += pn[(((size_t)bh*4 + s)*64 + a)*64 + d];
        den += pd[((size_t)bh*4 + s)*64 + a];
    }
    avT[(size_t)bh*4096 + d*64 + a] = (a < 49) ? f2bf(num / den) : (unsigned short)0;
}

// ---------------------------------------------------------------------------
// MFMA q-attention + fused depthwise conv (r8 LDS-diet version: 36.9 KB
// union, out_s [128][66] two half-passes, 4 blocks/CU).
// ---------------------------------------------------------------------------
__launch_bounds__(256)
__global__ void qattn_mfma_kernel(const unsigned short* __restrict__ qkv,
                                  const unsigned short* __restrict__ at_bf,
                                  const unsigned short* __restrict__ avT,
                                  const float* __restrict__ bias2,
                                  const float* __restrict__ dwc_w,
                                  const float* __restrict__ dwc_b,
                                  unsigned short* __restrict__ out_pre) {
    const int bh = blockIdx.x;
    const int b = bh >> 3, h = bh & 7;
    const int tq = blockIdx.y;
    __shared__ __align__(16) unsigned char smem[36864];   // P_s / out_s union
    unsigned short* P_s = (unsigned short*)smem;   // [4][64*72] bf16 (phase A)
    float* out_s = (float*)smem;                   // [128][66] f32  (phase B)
    __shared__ float dwcw_s[64*9];
    __shared__ float dwcb_s[64];
    const int tid = threadIdx.x;
    const int wid = tid >> 6, lane = tid & 63;
    const int l15 = lane & 15, quad = lane >> 4;
    const int j0  = tq*256 + wid*64;

    for (int i = tid; i < 64*9; i += 256) dwcw_s[i] = dwc_w[h*576 + i];
    if (tid < 64) dwcb_s[tid] = dwc_b[h*64 + tid];

    bf16x8 qa[4][2];
#pragma unroll
    for (int mt = 0; mt < 4; ++mt)
#pragma unroll
        for (int kf = 0; kf < 2; ++kf)
            qa[mt][kf] = *(const bf16x8*)
                (qkv + (size_t)(b*1024 + j0 + mt*16 + l15)*1536 + h*64 + kf*32 + quad*8);
    bf16x8 ab[4][2];
#pragma unroll
    for (int nt = 0; nt < 4; ++nt) {
        const int a  = nt*16 + l15;
        const int ar = (a < 49) ? a : 48;
#pragma unroll
        for (int kf = 0; kf < 2; ++kf)
            ab[nt][kf] = *(const bf16x8*)
                (at_bf + (size_t)(b*49 + ar)*512 + h*64 + kf*32 + quad*8);
    }

    f32x4 e[4][4];
#pragma unroll
    for (int i = 0; i < 4; ++i)
#pragma unroll
        for (int j = 0; j < 4; ++j) e[i][j] = (f32x4){0.f,0.f,0.f,0.f};
#pragma unroll
    for (int kf = 0; kf < 2; ++kf)
#pragma unroll
        for (int mt = 0; mt < 4; ++mt)
#pragma unroll
            for (int nt = 0; nt < 4; ++nt)
                e[mt][nt] = __builtin_amdgcn_mfma_f32_16x16x32_bf16(
                    qa[mt][kf], ab[nt][kf], e[mt][nt], 0, 0, 0);

    float denp[4][4];
#pragma unroll
    for (int mt = 0; mt < 4; ++mt)
#pragma unroll
        for (int r = 0; r < 4; ++r) denp[mt][r] = 0.f;
#pragma unroll
    for (int mt = 0; mt < 4; ++mt) {
#pragma unroll
        for (int nt = 0; nt < 4; ++nt) {
            const int a = nt*16 + l15;
#pragma unroll
            for (int r = 0; r < 4; ++r) {
                if (a < 49) {
                    const int jj = j0 + mt*16 + quad*4 + r;
                    const float v = __expf(fmaf(0.125f, e[mt][nt][r],
                                                bias2[((size_t)h*1024 + jj)*49 + a]));
                    e[mt][nt][r] = v;
                    denp[mt][r] += v;
                } else {
                    e[mt][nt][r] = 0.f;
                }
            }
        }
    }
#pragma unroll
    for (int mt = 0; mt < 4; ++mt) {
#pragma unroll
        for (int r = 0; r < 4; ++r) {
            float v = denp[mt][r];
            v += __shfl_xor(v, 1);
            v += __shfl_xor(v, 2);
            v += __shfl_xor(v, 4);
            v += __shfl_xor(v, 8);
            denp[mt][r] = 1.0f / v;
        }
    }
#pragma unroll
    for (int mt = 0; mt < 4; ++mt)
#pragma unroll
        for (int nt = 0; nt < 4; ++nt)
#pragma unroll
            for (int r = 0; r < 4; ++r)
                P_s[wid*4608 + (mt*16 + quad*4 + r)*72 + nt*16 + l15] =
                    f2bf(e[mt][nt][r] * denp[mt][r]);

    bf16x8 bv[4][2];
#pragma unroll
    for (int nt = 0; nt < 4; ++nt)
#pragma unroll
        for (int kf = 0; kf < 2; ++kf)
            bv[nt][kf] = *(const bf16x8*)
                (avT + (size_t)bh*4096 + (nt*16 + l15)*64 + kf*32 + quad*8);
    f32x4 out[4][4];
#pragma unroll
    for (int i = 0; i < 4; ++i)
#pragma unroll
        for (int j = 0; j < 4; ++j) out[i][j] = (f32x4){0.f,0.f,0.f,0.f};
#pragma unroll
    for (int kf = 0; kf < 2; ++kf) {
        bf16x8 pa[4];
#pragma unroll
        for (int mt = 0; mt < 4; ++mt)
            pa[mt] = *(const bf16x8*)(P_s + wid*4608 + (mt*16 + l15)*72 + kf*32 + quad*8);
#pragma unroll
        for (int nt = 0; nt < 4; ++nt)
#pragma unroll
            for (int mt = 0; mt < 4; ++mt)
                out[mt][nt] = __builtin_amdgcn_mfma_f32_16x16x32_bf16(
                    pa[mt], bv[nt][kf], out[mt][nt], 0, 0, 0);
    }

    __syncthreads();   // all waves done with P_s; re-carve smem as out_s

    const int tt = tid >> 2;
    const int p  = tid & 3;
    const int d0 = p*16;
#pragma unroll
    for (int pass = 0; pass < 2; ++pass) {
        if ((wid >> 1) == pass) {
#pragma unroll
            for (int mt = 0; mt < 4; ++mt)
#pragma unroll
                for (int nt = 0; nt < 4; ++nt)
#pragma unroll
                    for (int r = 0; r < 4; ++r)
                        out_s[((wid & 1)*64 + mt*16 + quad*4 + r)*66 + nt*16 + l15]
                            = out[mt][nt][r];
        }
        __syncthreads();
        for (int it = 0; it < 2; ++it) {
            const int tl = it*64 + tt;               // 0..127 (local row)
            const int jj = tq*256 + pass*128 + tl;   // global token
            float o[16];
#pragma unroll
            for (int i = 0; i < 16; ++i) o[i] = out_s[tl*66 + d0 + i] + dwcb_s[d0 + i];
            const int y = jj >> 5, x = jj & 31;
#pragma unroll
            for (int dy = 0; dy < 3; ++dy) {
                const int yy = y + dy - 1;
                if (yy < 0 || yy > 31) continue;
#pragma unroll
                for (int dx = 0; dx < 3; ++dx) {
                    const int xx = x + dx - 1;
                    if (xx < 0 || xx > 31) continue;
                    const unsigned short* vp =
                        qkv + (size_t)(b*1024 + yy*32 + xx)*1536 + 1024 + h*64 + d0;
#pragma unroll
                    for (int i4 = 0; i4 < 4; ++i4) {
                        const u16x4 v4 = *(const u16x4*)(vp + i4*4);
#pragma unroll
                        for (int i = 0; i < 4; ++i)
                            o[i4*4+i] = fmaf(dwcw_s[(d0 + i4*4 + i)*9 + dy*3 + dx],
                                             bf2f(v4[i]), o[i4*4+i]);
                    }
                }
            }
            unsigned short* op = out_pre + (size_t)(b*1024 + jj)*512 + h*64 + d0;
#pragma unroll
            for (int i4 = 0; i4 < 4; ++i4) {
                u16x4 w;
                w[0]=f2bf(o[i4*4+0]); w[1]=f2bf(o[i4*4+1]);
                w[2]=f2bf(o[i4*4+2]); w[3]=f2bf(o[i4*4+3]);
                *(u16x4*)(op + i4*4) = w;
            }
        }
        __syncthreads();
    }
}

// ---------------------------------------------------------------------------
extern "C" void kernel_launch(void* const* d_in, const int* in_sizes, int n_in,
                              void* d_out, int out_size, void* d_ws, size_t ws_size,
                              hipStream_t stream) {
    (void)in_sizes; (void)n_in; (void)out_size; (void)ws_size;
    const float* x       = (const float*)d_in[0];
    const float* context = (const float*)d_in[1];
    const float* Wq      = (const float*)d_in[2];
    const float* Wkv     = (const float*)d_in[3];
    const float* conv_w  = (const float*)d_in[4];
    const float* conv_b  = (const float*)d_in[5];
    const float* dwc_w   = (const float*)d_in[6];
    const float* dwc_b   = (const float*)d_in[7];
    const float* proj_w  = (const float*)d_in[8];
    const float* proj_b  = (const float*)d_in[9];
    const float* an_bias = (const float*)d_in[10];
    const float* na_bias = (const float*)d_in[11];
    const float* ah_bias = (const float*)d_in[12];
    const float* aw_bias = (const float*)d_in[13];
    const float* ha_bias = (const float*)d_in[14];
    const float* wa_bias = (const float*)d_in[15];

    char* ws = (char*)d_ws;
    size_t off = 0;
    auto alloc = [&](size_t bytes) -> char* {
        char* p = ws + off; off += (bytes + 255) & ~(size_t)255; return p;
    };
    unsigned short* xb     = (unsigned short*)alloc((size_t)16777216 * 2); // 33.5 MB
    unsigned short* qkv    = (unsigned short*)alloc((size_t)50331648 * 2);
    unsigned short* wqkvt  = (unsigned short*)alloc((size_t)786432  * 2);
    unsigned short* projwt = (unsigned short*)alloc((size_t)262144  * 2);
    unsigned short* convwb = (unsigned short*)alloc((size_t)3538944 * 2);
    unsigned short* i2c    = (unsigned short*)alloc((size_t)1664*6912*2);  // 23 MB
    unsigned short* at_bf  = (unsigned short*)alloc((size_t)1568*512*2);
    float*          bias1  = (float*)alloc((size_t)401408 * 4);
    float*          bias2  = (float*)alloc((size_t)401408 * 4);
    unsigned short* avT    = (unsigned short*)alloc((size_t)256*4096*2);
    // Aliases (stream-order safe): conv partials + outpre reuse xb after the
    // qkv GEMM finishes reading it; pn/pd reuse i2c after the conv GEMM.
    float*          part_conv = (float*)xb;
    float*          pn        = (float*)i2c;
    float*          pd        = pn + (size_t)256*4*64*64;
    unsigned short* outpre    = xb;

    // 1. all prep (x cvt + weight transposes + biases + conv_w cvt), 1 launch
    prep_all_kernel<<<37440, 256, 0, stream>>>(x, Wq, Wkv, proj_w, conv_w,
                                               an_bias, na_bias, ah_bias, aw_bias,
                                               ha_bias, wa_bias,
                                               xb, wqkvt, projwt, bias1, bias2, convwb);
    // 2. qkv = x @ [Wq|Wkv]  (M=32768, N=1536, K=512) -> bf16
    gemm_nt8<1><<<dim3(6, 128), 512, 0, stream>>>(xb, wqkvt, qkv, nullptr, 512, 1536);
    // 3. fused pool+im2col (writes i2c directly, no pooled buffer)
    pool_i2c_kernel<<<512, 256, 0, stream>>>(qkv, context, i2c);
    // 4. conv as split-K GEMM (M=1568 pad 1664, N=512, K=6912, 9 slices of 768)
    gemm_nt<3><<<dim3(4, 13, 9), 256, 0, stream>>>(i2c, convwb, part_conv, nullptr, 6912, 512, 768);
    // 5. reduce partials -> bf16 a_t
    convred_kernel<<<784, 256, 0, stream>>>(part_conv, conv_b, at_bf);
    // 6. MFMA agent attention, 4 j-slices + combine (emits avT bf16)
    agent_attn_mfma_kernel<<<dim3(256, 4), 256, 0, stream>>>(qkv, at_bf, bias1, pn, pd);
    agent_combine_kernel<<<4096, 256, 0, stream>>>(pn, pd, avT);
    // 7. MFMA q-attention + fused dwc
    qattn_mfma_kernel<<<dim3(256, 4), 256, 0, stream>>>(qkv, at_bf, avT, bias2,
                                                        dwc_w, dwc_b, outpre);
    // 8. final: out_pre @ proj_w + proj_b  (M=32768, N=512, K=512) -> f32
    gemm_nt8<0><<<dim3(2, 128), 512, 0, stream>>>(outpre, projwt, d_out, proj_b, 512, 512);
}

// Round 10
// 470.355 us; speedup vs baseline: 1.2443x; 1.2443x over previous
//
#include <hip/hip_runtime.h>
#include <stdint.h>

// ---------------------------------------------------------------------------
// Problem constants (fixed by setup_inputs)
// b=32, n=1024, dim=512, ic=512, cc=256, nh=8, ag=49, hd=64, H=W=c_H=c_W=32
// ---------------------------------------------------------------------------

typedef __attribute__((ext_vector_type(8)))  short          bf16x8;
typedef __attribute__((ext_vector_type(4)))  float          f32x4;
typedef __attribute__((ext_vector_type(4)))  unsigned short u16x4;

__device__ __forceinline__ float bf2f(unsigned short u) {
    union { unsigned int i; float f; } x; x.i = ((unsigned int)u) << 16; return x.f;
}
__device__ __forceinline__ unsigned short f2bf(float f) {
    union { float f; unsigned int i; } x; x.f = f;
    unsigned int i = x.i;
    i += 0x7FFFu + ((i >> 16) & 1u);   // RNE
    return (unsigned short)(i >> 16);
}

// ---------------------------------------------------------------------------
// Bias precompute helpers (bilinear 7->32, clamp edges)
// ---------------------------------------------------------------------------
__device__ __forceinline__ void bilin_coef(int i, int& i0, int& i1, float& f) {
    float pos = (i + 0.5f) * (7.0f / 32.0f) - 0.5f;
    float fl = floorf(pos);
    i0 = (int)fl; f = pos - fl;
    if (i0 < 0)       { i0 = 0; i1 = 0; f = 0.f; }
    else if (i0 >= 6) { i0 = 6; i1 = 6; f = 0.f; }
    else              { i1 = i0 + 1; }
}
__device__ __forceinline__ float bilin7(const float* __restrict__ s, int y, int x) {
    int y0,y1,x0,x1; float fy,fx;
    bilin_coef(y, y0, y1, fy); bilin_coef(x, x0, x1, fx);
    return (1.f-fy)*((1.f-fx)*s[y0*7+x0] + fx*s[y0*7+x1])
         +      fy *((1.f-fx)*s[y1*7+x0] + fx*s[y1*7+x1]);
}

// ---------------------------------------------------------------------------
// Merged prep kernel (kept from r9: + x->bf16 cvt; 6-in-1, one launch).
// r9 post-mortem: this merge is mechanism-safe (pure streaming, huge grid);
// the regression was entirely the fused pool+im2col (189us, 512-block
// latency-bound serial chain) — that fusion is reverted below.
// Ranges: [0,4194304) x cvt x4 | wqkvt 786432 | projwt 262144
//         | bias1 401408 | bias2 401408 | convwb 3538944.
// ---------------------------------------------------------------------------
__global__ void prep_all_kernel(const float* __restrict__ x,
                                const float* __restrict__ Wq,
                                const float* __restrict__ Wkv,
                                const float* __restrict__ Wproj,
                                const float* __restrict__ conv_w,
                                const float* __restrict__ an, const float* __restrict__ na,
                                const float* __restrict__ ah, const float* __restrict__ aw,
                                const float* __restrict__ ha, const float* __restrict__ wa,
                                unsigned short* __restrict__ xb,
                                unsigned short* __restrict__ wqkvt,
                                unsigned short* __restrict__ projwt,
                                float* __restrict__ bias1,
                                float* __restrict__ bias2,
                                unsigned short* __restrict__ convwb) {
    int idx = blockIdx.x * 256 + threadIdx.x;
    if (idx < 4194304) {
        const int i = idx * 4;
        const f32x4 v = *(const f32x4*)(x + i);
        u16x4 o; o[0]=f2bf(v[0]); o[1]=f2bf(v[1]); o[2]=f2bf(v[2]); o[3]=f2bf(v[3]);
        *(u16x4*)(xb + i) = o;
        return;
    }
    idx -= 4194304;
    if (idx < 786432) {
        const int nn = idx >> 9, kk = idx & 511;
        float v = (nn < 512) ? Wq[kk*512 + nn] : Wkv[kk*1024 + (nn - 512)];
        wqkvt[idx] = f2bf(v);
        return;
    }
    idx -= 786432;
    if (idx < 262144) {
        const int nn = idx >> 9, kk = idx & 511;
        projwt[idx] = f2bf(Wproj[kk*512 + nn]);
        return;
    }
    idx -= 262144;
    if (idx < 8*49*1024) {
        const int nn = idx & 1023;
        const int a  = (idx >> 10) % 49;
        const int h  = idx / (49*1024);
        const int y = nn >> 5, xq = nn & 31;
        float v = bilin7(an + (h*49 + a)*49, y, xq)
                + ah[(h*49 + a)*32 + y] + aw[(h*49 + a)*32 + xq];
        bias1[idx] = v;
        return;
    }
    idx -= 8*49*1024;
    if (idx < 8*1024*49) {
        const int a  = idx % 49;
        const int nn = (idx / 49) & 1023;
        const int h  = idx / (49*1024);
        const int y = nn >> 5, xq = nn & 31;
        float v = bilin7(na + (h*49 + a)*49, y, xq)
                + ha[h*1568 + y*49 + a] + wa[h*1568 + xq*49 + a];
        bias2[idx] = v;
        return;
    }
    idx -= 8*1024*49;
    if (idx < 3538944) convwb[idx] = f2bf(conv_w[idx]);
}

// ---------------------------------------------------------------------------
// Adaptive avg-pool 32x32 -> 7x7 (r8-verified separate kernel, restored).
// pooled flat layout per batch: a*768 + c.  4704 blocks -> full TLP.
// ---------------------------------------------------------------------------
__global__ void pool_kernel(const unsigned short* __restrict__ qkv,
                            const float* __restrict__ context,
                            float* __restrict__ pooled) {
    const int idx = blockIdx.x * 256 + threadIdx.x;   // b*37632 + a*768 + c
    if (idx >= 32*49*768) return;
    const int c = idx % 768;
    const int a = (idx / 768) % 49;
    const int b = idx / (768*49);
    const int p = a / 7, q = a % 7;
    const int ys = p*32/7, ye = (p*32 + 38)/7;
    const int xs = q*32/7, xe = (q*32 + 38)/7;
    float s = 0.f;
    if (c < 512) {
        for (int y = ys; y < ye; ++y)
            for (int x = xs; x < xe; ++x)
                s += bf2f(qkv[(size_t)(b*1024 + y*32 + x)*1536 + c]);
    } else {
        for (int y = ys; y < ye; ++y)
            for (int x = xs; x < xe; ++x)
                s += context[(size_t)(b*1024 + y*32 + x)*256 + (c - 512)];
    }
    pooled[idx] = s / (float)((ye - ys)*(xe - xs));
}

// im2col (r8-verified, restored): out[(b*49 + p*7+q)*6912 + ci*9 + dy*3 + dx]
__global__ void im2col_kernel(const float* __restrict__ pooled,
                              unsigned short* __restrict__ i2c) {
    const int idx = blockIdx.x * 256 + threadIdx.x;
    if (idx >= 1568*6912) return;
    const int kk = idx % 6912;
    const int m  = idx / 6912;
    const int b = m / 49, spq = m % 49;
    const int p = spq / 7, q = spq % 7;
    const int ci = kk / 9, r = kk % 9;
    const int dy = r / 3, dx = r % 3;
    const int yy = p + dy - 1, xx = q + dx - 1;
    float v = 0.f;
    if (yy >= 0 && yy < 7 && xx >= 0 && xx < 7)
        v = pooled[b*37632 + ci*49 + yy*7 + xx];
    i2c[idx] = f2bf(v);
}

// ---------------------------------------------------------------------------
// NT bf16 MFMA GEMM (m97 structure) — conv split-K GEMM. MODE 3 only.
// ---------------------------------------------------------------------------
template <int MODE>
__launch_bounds__(256)
__global__ void gemm_nt(const unsigned short* __restrict__ A,
                        const unsigned short* __restrict__ Bt,
                        void* __restrict__ C,
                        const float* __restrict__ bias,
                        int K, int ldc, int kspan) {
    __shared__ __align__(16) unsigned char smem_raw[32768];
    unsigned short* As = (unsigned short*)smem_raw;           // [128][64] bf16
    unsigned short* Bs = (unsigned short*)(smem_raw + 16384); // [128][64] bf16

    // ---- T1 swizzle ----
    const int gx  = gridDim.x;
    const int gxy = gridDim.x * gridDim.y;
    const int nwg = gxy * gridDim.z;
    const int L   = (blockIdx.z * gridDim.y + blockIdx.y) * gx + blockIdx.x;
    const int qq  = nwg >> 3, rr = nwg & 7;
    const int xcd = L & 7,   ii = L >> 3;
    const int W   = (xcd < rr ? xcd * (qq + 1) : rr * (qq + 1) + (xcd - rr) * qq) + ii;
    const int bz  = W / gxy;
    const int rem = W - bz * gxy;
    const int by  = rem / gx;
    const int bx  = rem - by * gx;

    const int tid  = threadIdx.x;
    const int wid  = tid >> 6;
    const int lane = tid & 63;
    const int m0 = by * 128;
    const int n0 = bx * 128;
    const int wm = (wid >> 1) * 64;
    const int wn = (wid & 1) * 64;
    const int lrow = lane & 15;
    const int quad = lane >> 4;
    const int srow = lane >> 3;
    const int scol = ((lane & 7) ^ srow) * 8;

    f32x4 acc[4][4];
#pragma unroll
    for (int i = 0; i < 4; ++i)
#pragma unroll
        for (int j = 0; j < 4; ++j) acc[i][j] = (f32x4){0.f,0.f,0.f,0.f};

    const int kz0 = bz * kspan;
    const int kz1 = min(K, kz0 + kspan);
    for (int k0 = kz0; k0 < kz1; k0 += 64) {
        __syncthreads();
#pragma unroll
        for (int i = 0; i < 4; ++i) {
            const int chunk = wid*4 + i;
            const int row = chunk*8 + srow;
            __builtin_amdgcn_global_load_lds(
                (const __attribute__((address_space(1))) void*)(A + (size_t)(m0 + row)*K + k0 + scol),
                (__attribute__((address_space(3))) void*)(As + chunk*512), 16, 0, 0);
            __builtin_amdgcn_global_load_lds(
                (const __attribute__((address_space(1))) void*)(Bt + (size_t)(n0 + row)*K + k0 + scol),
                (__attribute__((address_space(3))) void*)(Bs + chunk*512), 16, 0, 0);
        }
        __syncthreads();
#pragma unroll
        for (int kk = 0; kk < 2; ++kk) {
            bf16x8 af[4], bfr[4];
#pragma unroll
            for (int mt = 0; mt < 4; ++mt) {
                const int row = wm + mt*16 + lrow;
                const int u = (kk*4 + quad) ^ (row & 7);
                af[mt] = *(const bf16x8*)(As + row*64 + u*8);
            }
#pragma unroll
            for (int nt = 0; nt < 4; ++nt) {
                const int row = wn + nt*16 + lrow;
                const int u = (kk*4 + quad) ^ (row & 7);
                bfr[nt] = *(const bf16x8*)(Bs + row*64 + u*8);
            }
#pragma unroll
            for (int mt = 0; mt < 4; ++mt)
#pragma unroll
                for (int nt = 0; nt < 4; ++nt)
                    acc[mt][nt] = __builtin_amdgcn_mfma_f32_16x16x32_bf16(
                        af[mt], bfr[nt], acc[mt][nt], 0, 0, 0);
        }
    }

    // ---- LDS-staged epilogue (f32 modes) ----
    __syncthreads();
    {
        float* Cf = (float*)smem_raw;                     // [64][128] f32, XOR-swz
#pragma unroll
        for (int half = 0; half < 2; ++half) {
            if ((wid >> 1) == half) {
#pragma unroll
                for (int mt = 0; mt < 4; ++mt)
#pragma unroll
                    for (int nt = 0; nt < 4; ++nt)
#pragma unroll
                        for (int r = 0; r < 4; ++r) {
                            const int mr = mt*16 + quad*4 + r;
                            const int n  = wn + nt*16 + lrow;
                            Cf[mr*128 + (n ^ ((mr & 7) << 2))] = acc[mt][nt][r];
                        }
            }
            __syncthreads();
#pragma unroll
            for (int it = 0; it < 8; ++it) {
                const int idx = it*256 + tid;
                const int row = idx >> 5, c4 = idx & 31;
                const int m = m0 + half*64 + row;
                f32x4 v = *(const f32x4*)(Cf + row*128 + ((c4*4) ^ ((row & 7) << 2)));
                if (MODE == 0) {
                    const f32x4 bb = *(const f32x4*)(bias + n0 + c4*4);
                    v[0]+=bb[0]; v[1]+=bb[1]; v[2]+=bb[2]; v[3]+=bb[3];
                    *(f32x4*)((float*)C + (size_t)m*ldc + n0 + c4*4) = v;
                } else {
                    if (m < 1568)
                        *(f32x4*)((float*)C + ((size_t)bz*1568 + m)*512 + n0 + c4*4) = v;
                }
            }
            __syncthreads();
        }
    }
}

// ---------------------------------------------------------------------------
// 256x256 8-phase pipelined NT bf16 GEMM (T3+T4+T5+T2, verified r5).
// MODE 0: f32 C + bias (proj)    MODE 1: bf16 C (qkv)
// ---------------------------------------------------------------------------
#define STAGE_A(DST, T, Q) do {                                                             \
    _Pragma("unroll")                                                                       \
    for (int l_ = 0; l_ < 2; ++l_) {                                                        \
        const int rb_ = l_*128 + (Q)*64 + wid*8;                                            \
        __builtin_amdgcn_global_load_lds(                                                   \
            (const __attribute__((address_space(1))) void*)                                 \
                (Ag + (size_t)(m0 + rb_ + lr8)*K + (T)*64 + scl),                           \
            (__attribute__((address_space(3))) void*)((DST) + rb_*64), 16, 0, 0);           \
    }                                                                                       \
} while (0)

#define STAGE_B(DST, T, NH) do {                                                            \
    _Pragma("unroll")                                                                       \
    for (int l_ = 0; l_ < 2; ++l_) {                                                        \
        const int w8_ = wid*8;                                                              \
        const int rb_ = l_*128 + ((w8_ >> 5) << 6) + (NH)*32 + (w8_ & 31);                  \
        __builtin_amdgcn_global_load_lds(                                                   \
            (const __attribute__((address_space(1))) void*)                                 \
                (Btg + (size_t)(n0 + rb_ + lr8)*K + (T)*64 + scl),                          \
            (__attribute__((address_space(3))) void*)((DST) + rb_*64), 16, 0, 0);           \
    }                                                                                       \
} while (0)

#define LOAD_A(MH, SRC) do {                                                                \
    _Pragma("unroll")                                                                       \
    for (int m4_ = 0; m4_ < 4; ++m4_)                                                       \
    _Pragma("unroll")                                                                       \
    for (int kk_ = 0; kk_ < 2; ++kk_)                                                       \
        aF[m4_][kk_] = *(const bf16x8*)                                                     \
            ((SRC) + (wr*128 + ((MH)*4 + m4_)*16 + l15)*64                                  \
                   + (((kk_*4 + quad) ^ sw7) * 8));                                         \
} while (0)

#define LOAD_B(NH, DSTF, SRC) do {                                                          \
    _Pragma("unroll")                                                                       \
    for (int n2_ = 0; n2_ < 2; ++n2_)                                                       \
    _Pragma("unroll")                                                                       \
    for (int kk_ = 0; kk_ < 2; ++kk_)                                                       \
        DSTF[n2_][kk_] = *(const bf16x8*)                                                   \
            ((SRC) + (wc*64 + ((NH)*2 + n2_)*16 + l15)*64                                   \
                   + (((kk_*4 + quad) ^ sw7) * 8));                                         \
} while (0)

#define MFMA_PHASE(MH, NH, BF) do {                                                         \
    __builtin_amdgcn_s_barrier();                                                           \
    asm volatile("s_waitcnt lgkmcnt(0)");                                                   \
    __builtin_amdgcn_sched_barrier(0);                                                      \
    __builtin_amdgcn_s_setprio(1);                                                          \
    _Pragma("unroll")                                                                       \
    for (int kk_ = 0; kk_ < 2; ++kk_)                                                       \
    _Pragma("unroll")                                                                       \
    for (int m4_ = 0; m4_ < 4; ++m4_)                                                       \
    _Pragma("unroll")                                                                       \
    for (int n2_ = 0; n2_ < 2; ++n2_)                                                       \
        acc[(MH)*4 + m4_][(NH)*2 + n2_] = __builtin_amdgcn_mfma_f32_16x16x32_bf16(          \
            aF[m4_][kk_], BF[n2_][kk_], acc[(MH)*4 + m4_][(NH)*2 + n2_], 0, 0, 0);          \
    __builtin_amdgcn_s_setprio(0);                                                          \
    __builtin_amdgcn_sched_barrier(0);                                                      \
} while (0)

template <int MODE>
__launch_bounds__(512, 1)
__global__ void gemm_nt8(const unsigned short* __restrict__ Ag,
                         const unsigned short* __restrict__ Btg,
                         void* __restrict__ C,
                         const float* __restrict__ bias,
                         int K, int ldc) {
    __shared__ unsigned short AsB[2][16384];
    __shared__ unsigned short BsB[2][16384];

    const int gx  = gridDim.x;
    const int nwg = gx * gridDim.y;
    const int L   = blockIdx.y * gx + blockIdx.x;
    const int qq  = nwg >> 3, rr = nwg & 7;
    const int xcd = L & 7,   ii = L >> 3;
    const int W   = (xcd < rr ? xcd * (qq + 1) : rr * (qq + 1) + (xcd - rr) * qq) + ii;
    const int bx  = W % gx, by = W / gx;
    const int m0  = by * 256, n0 = bx * 256;

    const int tid  = threadIdx.x;
    const int wid  = tid >> 6, lane = tid & 63;
    const int wr   = wid >> 2, wc = wid & 3;
    const int l15  = lane & 15, quad = lane >> 4;
    const int lr8  = lane >> 3;
    const int scl  = ((lane & 7) ^ lr8) * 8;
    const int sw7  = l15 & 7;
    const int KT   = K >> 6;

    unsigned short *Acur = &AsB[0][0], *Anxt = &AsB[1][0];
    unsigned short *Bcur = &BsB[0][0], *Bnxt = &BsB[1][0];

    f32x4 acc[8][4];
#pragma unroll
    for (int i = 0; i < 8; ++i)
#pragma unroll
        for (int j = 0; j < 4; ++j) acc[i][j] = (f32x4){0.f,0.f,0.f,0.f};

    bf16x8 aF[4][2], bF0[2][2], bF1[2][2];

    STAGE_A(Acur, 0, 0); STAGE_B(Bcur, 0, 1); STAGE_A(Acur, 0, 1); STAGE_B(Bcur, 0, 0);
    STAGE_A(Anxt, 1, 0); STAGE_B(Bnxt, 1, 1); STAGE_A(Anxt, 1, 1);
    asm volatile("s_waitcnt vmcnt(6)");
    __builtin_amdgcn_s_barrier();

    for (int t = 0; t < KT; ++t) {
        LOAD_B(0, bF0, Bcur);
        LOAD_A(0, Acur);
        if (t + 1 < KT) STAGE_B(Bnxt, t + 1, 0);
        MFMA_PHASE(0, 0, bF0);
        __builtin_amdgcn_s_barrier();

        LOAD_B(1, bF1, Bcur);
        if (t + 2 < KT) STAGE_A(Acur, t + 2, 0);
        MFMA_PHASE(0, 1, bF1);
        __builtin_amdgcn_s_barrier();

        LOAD_A(1, Acur);
        if (t + 2 < KT) STAGE_B(Bcur, t + 2, 1);
        MFMA_PHASE(1, 1, bF1);
        __builtin_amdgcn_s_barrier();

        LOAD_B(0, bF0, Bcur);
        if (t + 2 < KT) STAGE_A(Acur, t + 2, 1);
        MFMA_PHASE(1, 0, bF0);
        if (t + 2 < KT) asm volatile("s_waitcnt vmcnt(6)");
        else            asm volatile("s_waitcnt vmcnt(0)");
        __builtin_amdgcn_s_barrier();

        unsigned short* tmp;
        tmp = Acur; Acur = Anxt; Anxt = tmp;
        tmp = Bcur; Bcur = Bnxt; Bnxt = tmp;
    }

    if (MODE == 1) {
#pragma unroll
        for (int mt = 0; mt < 8; ++mt)
#pragma unroll
            for (int nt = 0; nt < 4; ++nt)
#pragma unroll
                for (int r = 0; r < 4; ++r) {
                    const int m = m0 + wr*128 + mt*16 + quad*4 + r;
                    const int n = n0 + wc*64  + nt*16 + l15;
                    ((unsigned short*)C)[(size_t)m*ldc + n] = f2bf(acc[mt][nt][r]);
                }
    } else {
        float bv[4];
#pragma unroll
        for (int nt = 0; nt < 4; ++nt) bv[nt] = bias[n0 + wc*64 + nt*16 + l15];
#pragma unroll
        for (int mt = 0; mt < 8; ++mt)
#pragma unroll
            for (int nt = 0; nt < 4; ++nt)
#pragma unroll
                for (int r = 0; r < 4; ++r) {
                    const int m = m0 + wr*128 + mt*16 + quad*4 + r;
                    const int n = n0 + wc*64  + nt*16 + l15;
                    ((float*)C)[(size_t)m*ldc + n] = acc[mt][nt][r] + bv[nt];
                }
    }
}

#undef STAGE_A
#undef STAGE_B
#undef LOAD_A
#undef LOAD_B
#undef MFMA_PHASE

// Sum 9 split-K partials, add conv bias, emit bf16 a_t.
__global__ void convred_kernel(const float* __restrict__ part,
                               const float* __restrict__ bias,
                               unsigned short* __restrict__ at_bf) {
    const int idx = blockIdx.x * 256 + threadIdx.x;   // over 1568*128
    if (idx >= 1568*128) return;
    const int m  = idx >> 7;
    const int n4 = (idx & 127) * 4;
    f32x4 s = *(const f32x4*)&part[(size_t)m*512 + n4];
#pragma unroll
    for (int kz = 1; kz < 9; ++kz) {
        const f32x4 p = *(const f32x4*)&part[((size_t)kz*1568 + m)*512 + n4];
        s[0]+=p[0]; s[1]+=p[1]; s[2]+=p[2]; s[3]+=p[3];
    }
    u16x4 o;
    o[0] = f2bf(s[0] + bias[n4+0]);
    o[1] = f2bf(s[1] + bias[n4+1]);
    o[2] = f2bf(s[2] + bias[n4+2]);
    o[3] = f2bf(s[3] + bias[n4+3]);
    *(u16x4*)&at_bf[(size_t)m*512 + n4] = o;
}

// ---------------------------------------------------------------------------
// MFMA agent attention. Grid (256 bh, 4 slices), 256 thr (4 waves).
// ---------------------------------------------------------------------------
__launch_bounds__(256)
__global__ void agent_attn_mfma_kernel(const unsigned short* __restrict__ qkv,
                                       const unsigned short* __restrict__ at_bf,
                                       const float* __restrict__ bias1,
                                       float* __restrict__ pn,
                                       float* __restrict__ pd) {
    const int bh = blockIdx.x;
    const int b = bh >> 3, h = bh & 7;
    const int sl = blockIdx.y;
    __shared__ unsigned short at_s[64*72];
    __shared__ __align__(16) unsigned char smem[4*64*72*2 + 4*64*64*2];
    unsigned short* P_s = (unsigned short*)smem;
    unsigned short* V_s = (unsigned short*)(smem + 36864);
    float* red  = (float*)smem;
    float* dred = (float*)(smem + 65536);
    const int tid  = threadIdx.x;
    const int wid  = tid >> 6, lane = tid & 63;
    const int l15  = lane & 15, quad = lane >> 4;
    const int j0   = sl*256 + wid*64;

    for (int i = tid; i < 64*72; i += 256) at_s[i] = 0;
    __syncthreads();
    for (int i = tid; i < 49*16; i += 256) {
        const int a = i >> 4, dq = (i & 15) * 4;
        *(u16x4*)&at_s[a*72 + dq] = *(const u16x4*)&at_bf[(size_t)(b*49 + a)*512 + h*64 + dq];
    }
#pragma unroll
    for (int i = 0; i < 8; ++i) {
        __builtin_amdgcn_global_load_lds(
            (const __attribute__((address_space(1))) void*)
                (qkv + (size_t)(b*1024 + j0 + i*8 + (lane>>3))*1536 + 1024 + h*64 + (lane&7)*8),
            (__attribute__((address_space(3))) void*)(V_s + wid*4096 + i*512), 16, 0, 0);
    }
    bf16x8 kfr[4][2];
#pragma unroll
    for (int nt = 0; nt < 4; ++nt)
#pragma unroll
        for (int kf = 0; kf < 2; ++kf)
            kfr[nt][kf] = *(const bf16x8*)
                (qkv + (size_t)(b*1024 + j0 + nt*16 + l15)*1536 + 512 + h*64 + kf*32 + quad*8);
    __syncthreads();

    bf16x8 af[4][2];
#pragma unroll
    for (int mt = 0; mt < 4; ++mt)
#pragma unroll
        for (int kf = 0; kf < 2; ++kf)
            af[mt][kf] = *(const bf16x8*)(at_s + (mt*16 + l15)*72 + kf*32 + quad*8);

    f32x4 acc[4][4];
#pragma unroll
    for (int i = 0; i < 4; ++i)
#pragma unroll
        for (int j = 0; j < 4; ++j) acc[i][j] = (f32x4){0.f,0.f,0.f,0.f};
#pragma unroll
    for (int kf = 0; kf < 2; ++kf)
#pragma unroll
        for (int mt = 0; mt < 4; ++mt)
#pragma unroll
            for (int nt = 0; nt < 4; ++nt)
                acc[mt][nt] = __builtin_amdgcn_mfma_f32_16x16x32_bf16(
                    af[mt][kf], kfr[nt][kf], acc[mt][nt], 0, 0, 0);

    float denp[4][4];
#pragma unroll
    for (int mt = 0; mt < 4; ++mt)
#pragma unroll
        for (int r = 0; r < 4; ++r) denp[mt][r] = 0.f;
#pragma unroll
    for (int mt = 0; mt < 4; ++mt) {
#pragma unroll
        for (int nt = 0; nt < 4; ++nt) {
#pragma unroll
            for (int r = 0; r < 4; ++r) {
                const int a  = mt*16 + quad*4 + r;
                const int ab = (a < 49) ? a : 48;
                const int jj = j0 + nt*16 + l15;
                const float e = __expf(fmaf(0.125f, acc[mt][nt][r],
                                            bias1[(h*49 + ab)*1024 + jj]));
                denp[mt][r] += e;
                P_s[wid*4608 + a*72 + nt*16 + l15] = f2bf(e);
            }
        }
    }
    __syncthreads();

    f32x4 out[4][4];
#pragma unroll
    for (int i = 0; i < 4; ++i)
#pragma unroll
        for (int j = 0; j < 4; ++j) out[i][j] = (f32x4){0.f,0.f,0.f,0.f};
#pragma unroll
    for (int kf = 0; kf < 2; ++kf) {
        bf16x8 va[4];
#pragma unroll
        for (int mt = 0; mt < 4; ++mt) {
            union { bf16x8 v; unsigned short s[8]; } u;
#pragma unroll
            for (int t = 0; t < 8; ++t)
                u.s[t] = V_s[wid*4096 + (kf*32 + quad*8 + t)*64 + mt*16 + l15];
            va[mt] = u.v;
        }
#pragma unroll
        for (int nt = 0; nt < 4; ++nt) {
            const bf16x8 pb = *(const bf16x8*)(P_s + wid*4608 + (nt*16 + l15)*72 + kf*32 + quad*8);
#pragma unroll
            for (int mt = 0; mt < 4; ++mt)
                out[mt][nt] = __builtin_amdgcn_mfma_f32_16x16x32_bf16(
                    va[mt], pb, out[mt][nt], 0, 0, 0);
        }
    }

#pragma unroll
    for (int mt = 0; mt < 4; ++mt) {
#pragma unroll
        for (int r = 0; r < 4; ++r) {
            float v = denp[mt][r];
            v += __shfl_xor(v, 1);
            v += __shfl_xor(v, 2);
            v += __shfl_xor(v, 4);
            v += __shfl_xor(v, 8);
            denp[mt][r] = v;
        }
    }

    __syncthreads();
#pragma unroll
    for (int nt = 0; nt < 4; ++nt) {
        const int a = nt*16 + l15;
#pragma unroll
        for (int mt = 0; mt < 4; ++mt)
            *(f32x4*)&red[wid*4096 + a*64 + mt*16 + quad*4] = out[mt][nt];
    }
    if (l15 == 0) {
#pragma unroll
        for (int mt = 0; mt < 4; ++mt)
#pragma unroll
            for (int r = 0; r < 4; ++r)
                dred[wid*64 + mt*16 + quad*4 + r] = denp[mt][r];
    }
    __syncthreads();
    for (int i = tid; i < 4096; i += 256) {
        const float s = red[i] + red[4096 + i] + red[8192 + i] + red[12288 + i];
        pn[((size_t)bh*4 + sl)*4096 + i] = s;
    }
    if (tid < 64) {
        const float s = dred[tid] + dred[64 + tid] + dred[128 + tid] + dred[192 + tid];
        pd[((size_t)bh*4 + sl)*64 + tid] = s;
    }
}

// Combine 4 j-slice partials; emit bf16 agent_v transposed [bh][d][a-pad-64].
__global__ void agent_combine_kernel(const float* __restrict__ pn,
                                     const float* __restrict__ pd,
                                     unsigned short* __restrict__ avT) {
    const int idx = blockIdx.x * 256 + threadIdx.x;
    if (idx >= 256*4096) return;
    const int bh = idx >> 12;
    const int i  = idx & 4095;
    const int a = i >> 6, d = i & 63;
    float num = 0.f, den = 0.f;
#pragma unroll
    for (int s = 0; s < 4; ++s) {
        num += pn[(((size_t)bh*4 + s)*64 + a)*64 + d];
        den += pd[((size_t)bh*4 + s)*64 + a];
    }
    avT[(size_t)bh*4096 + d*64 + a] = (a < 49) ? f2bf(num / den) : (unsigned short)0;
}

// ---------------------------------------------------------------------------
// MFMA q-attention + fused depthwise conv (r8 LDS-diet version: 36.9 KB
// union, out_s [128][66] two half-passes, 4 blocks/CU).
// ---------------------------------------------------------------------------
__launch_bounds__(256)
__global__ void qattn_mfma_kernel(const unsigned short* __restrict__ qkv,
                                  const unsigned short* __restrict__ at_bf,
                                  const unsigned short* __restrict__ avT,
                                  const float* __restrict__ bias2,
                                  const float* __restrict__ dwc_w,
                                  const float* __restrict__ dwc_b,
                                  unsigned short* __restrict__ out_pre) {
    const int bh = blockIdx.x;
    const int b = bh >> 3, h = bh & 7;
    const int tq = blockIdx.y;
    __shared__ __align__(16) unsigned char smem[36864];   // P_s / out_s union
    unsigned short* P_s = (unsigned short*)smem;   // [4][64*72] bf16 (phase A)
    float* out_s = (float*)smem;                   // [128][66] f32  (phase B)
    __shared__ float dwcw_s[64*9];
    __shared__ float dwcb_s[64];
    const int tid = threadIdx.x;
    const int wid = tid >> 6, lane = tid & 63;
    const int l15 = lane & 15, quad = lane >> 4;
    const int j0  = tq*256 + wid*64;

    for (int i = tid; i < 64*9; i += 256) dwcw_s[i] = dwc_w[h*576 + i];
    if (tid < 64) dwcb_s[tid] = dwc_b[h*64 + tid];

    bf16x8 qa[4][2];
#pragma unroll
    for (int mt = 0; mt < 4; ++mt)
#pragma unroll
        for (int kf = 0; kf < 2; ++kf)
            qa[mt][kf] = *(const bf16x8*)
                (qkv + (size_t)(b*1024 + j0 + mt*16 + l15)*1536 + h*64 + kf*32 + quad*8);
    bf16x8 ab[4][2];
#pragma unroll
    for (int nt = 0; nt < 4; ++nt) {
        const int a  = nt*16 + l15;
        const int ar = (a < 49) ? a : 48;
#pragma unroll
        for (int kf = 0; kf < 2; ++kf)
            ab[nt][kf] = *(const bf16x8*)
                (at_bf + (size_t)(b*49 + ar)*512 + h*64 + kf*32 + quad*8);
    }

    f32x4 e[4][4];
#pragma unroll
    for (int i = 0; i < 4; ++i)
#pragma unroll
        for (int j = 0; j < 4; ++j) e[i][j] = (f32x4){0.f,0.f,0.f,0.f};
#pragma unroll
    for (int kf = 0; kf < 2; ++kf)
#pragma unroll
        for (int mt = 0; mt < 4; ++mt)
#pragma unroll
            for (int nt = 0; nt < 4; ++nt)
                e[mt][nt] = __builtin_amdgcn_mfma_f32_16x16x32_bf16(
                    qa[mt][kf], ab[nt][kf], e[mt][nt], 0, 0, 0);

    float denp[4][4];
#pragma unroll
    for (int mt = 0; mt < 4; ++mt)
#pragma unroll
        for (int r = 0; r < 4; ++r) denp[mt][r] = 0.f;
#pragma unroll
    for (int mt = 0; mt < 4; ++mt) {
#pragma unroll
        for (int nt = 0; nt < 4; ++nt) {
            const int a = nt*16 + l15;
#pragma unroll
            for (int r = 0; r < 4; ++r) {
                if (a < 49) {
                    const int jj = j0 + mt*16 + quad*4 + r;
                    const float v = __expf(fmaf(0.125f, e[mt][nt][r],
                                                bias2[((size_t)h*1024 + jj)*49 + a]));
                    e[mt][nt][r] = v;
                    denp[mt][r] += v;
                } else {
                    e[mt][nt][r] = 0.f;
                }
            }
        }
    }
#pragma unroll
    for (int mt = 0; mt < 4; ++mt) {
#pragma unroll
        for (int r = 0; r < 4; ++r) {
            float v = denp[mt][r];
            v += __shfl_xor(v, 1);
            v += __shfl_xor(v, 2);
            v += __shfl_xor(v, 4);
            v += __shfl_xor(v, 8);
            denp[mt][r] = 1.0f / v;
        }
    }
#pragma unroll
    for (int mt = 0; mt < 4; ++mt)
#pragma unroll
        for (int nt = 0; nt < 4; ++nt)
#pragma unroll
            for (int r = 0; r < 4; ++r)
                P_s[wid*4608 + (mt*16 + quad*4 + r)*72 + nt*16 + l15] =
                    f2bf(e[mt][nt][r] * denp[mt][r]);

    bf16x8 bv[4][2];
#pragma unroll
    for (int nt = 0; nt < 4; ++nt)
#pragma unroll
        for (int kf = 0; kf < 2; ++kf)
            bv[nt][kf] = *(const bf16x8*)
                (avT + (size_t)bh*4096 + (nt*16 + l15)*64 + kf*32 + quad*8);
    f32x4 out[4][4];
#pragma unroll
    for (int i = 0; i < 4; ++i)
#pragma unroll
        for (int j = 0; j < 4; ++j) out[i][j] = (f32x4){0.f,0.f,0.f,0.f};
#pragma unroll
    for (int kf = 0; kf < 2; ++kf) {
        bf16x8 pa[4];
#pragma unroll
        for (int mt = 0; mt < 4; ++mt)
            pa[mt] = *(const bf16x8*)(P_s + wid*4608 + (mt*16 + l15)*72 + kf*32 + quad*8);
#pragma unroll
        for (int nt = 0; nt < 4; ++nt)
#pragma unroll
            for (int mt = 0; mt < 4; ++mt)
                out[mt][nt] = __builtin_amdgcn_mfma_f32_16x16x32_bf16(
                    pa[mt], bv[nt][kf], out[mt][nt], 0, 0, 0);
    }

    __syncthreads();   // all waves done with P_s; re-carve smem as out_s

    const int tt = tid >> 2;
    const int p  = tid & 3;
    const int d0 = p*16;
#pragma unroll
    for (int pass = 0; pass < 2; ++pass) {
        if ((wid >> 1) == pass) {
#pragma unroll
            for (int mt = 0; mt < 4; ++mt)
#pragma unroll
                for (int nt = 0; nt < 4; ++nt)
#pragma unroll
                    for (int r = 0; r < 4; ++r)
                        out_s[((wid & 1)*64 + mt*16 + quad*4 + r)*66 + nt*16 + l15]
                            = out[mt][nt][r];
        }
        __syncthreads();
        for (int it = 0; it < 2; ++it) {
            const int tl = it*64 + tt;               // 0..127 (local row)
            const int jj = tq*256 + pass*128 + tl;   // global token
            float o[16];
#pragma unroll
            for (int i = 0; i < 16; ++i) o[i] = out_s[tl*66 + d0 + i] + dwcb_s[d0 + i];
            const int y = jj >> 5, x = jj & 31;
#pragma unroll
            for (int dy = 0; dy < 3; ++dy) {
                const int yy = y + dy - 1;
                if (yy < 0 || yy > 31) continue;
#pragma unroll
                for (int dx = 0; dx < 3; ++dx) {
                    const int xx = x + dx - 1;
                    if (xx < 0 || xx > 31) continue;
                    const unsigned short* vp =
                        qkv + (size_t)(b*1024 + yy*32 + xx)*1536 + 1024 + h*64 + d0;
#pragma unroll
                    for (int i4 = 0; i4 < 4; ++i4) {
                        const u16x4 v4 = *(const u16x4*)(vp + i4*4);
#pragma unroll
                        for (int i = 0; i < 4; ++i)
                            o[i4*4+i] = fmaf(dwcw_s[(d0 + i4*4 + i)*9 + dy*3 + dx],
                                             bf2f(v4[i]), o[i4*4+i]);
                    }
                }
            }
            unsigned short* op = out_pre + (size_t)(b*1024 + jj)*512 + h*64 + d0;
#pragma unroll
            for (int i4 = 0; i4 < 4; ++i4) {
                u16x4 w;
                w[0]=f2bf(o[i4*4+0]); w[1]=f2bf(o[i4*4+1]);
                w[2]=f2bf(o[i4*4+2]); w[3]=f2bf(o[i4*4+3]);
                *(u16x4*)(op + i4*4) = w;
            }
        }
        __syncthreads();
    }
}

// ---------------------------------------------------------------------------
extern "C" void kernel_launch(void* const* d_in, const int* in_sizes, int n_in,
                              void* d_out, int out_size, void* d_ws, size_t ws_size,
                              hipStream_t stream) {
    (void)in_sizes; (void)n_in; (void)out_size; (void)ws_size;
    const float* x       = (const float*)d_in[0];
    const float* context = (const float*)d_in[1];
    const float* Wq      = (const float*)d_in[2];
    const float* Wkv     = (const float*)d_in[3];
    const float* conv_w  = (const float*)d_in[4];
    const float* conv_b  = (const float*)d_in[5];
    const float* dwc_w   = (const float*)d_in[6];
    const float* dwc_b   = (const float*)d_in[7];
    const float* proj_w  = (const float*)d_in[8];
    const float* proj_b  = (const float*)d_in[9];
    const float* an_bias = (const float*)d_in[10];
    const float* na_bias = (const float*)d_in[11];
    const float* ah_bias = (const float*)d_in[12];
    const float* aw_bias = (const float*)d_in[13];
    const float* ha_bias = (const float*)d_in[14];
    const float* wa_bias = (const float*)d_in[15];

    char* ws = (char*)d_ws;
    size_t off = 0;
    auto alloc = [&](size_t bytes) -> char* {
        char* p = ws + off; off += (bytes + 255) & ~(size_t)255; return p;
    };
    unsigned short* xb     = (unsigned short*)alloc((size_t)16777216 * 2); // 33.5 MB
    unsigned short* qkv    = (unsigned short*)alloc((size_t)50331648 * 2);
    unsigned short* wqkvt  = (unsigned short*)alloc((size_t)786432  * 2);
    unsigned short* projwt = (unsigned short*)alloc((size_t)262144  * 2);
    unsigned short* convwb = (unsigned short*)alloc((size_t)3538944 * 2);
    float*          pooled = (float*)alloc((size_t)1204224 * 4);
    unsigned short* i2c    = (unsigned short*)alloc((size_t)1664*6912*2);  // 23 MB
    unsigned short* at_bf  = (unsigned short*)alloc((size_t)1568*512*2);
    float*          bias1  = (float*)alloc((size_t)401408 * 4);
    float*          bias2  = (float*)alloc((size_t)401408 * 4);
    unsigned short* avT    = (unsigned short*)alloc((size_t)256*4096*2);
    // Aliases (stream-order safe): conv partials + outpre reuse xb after the
    // qkv GEMM finishes reading it; pn/pd reuse i2c after the conv GEMM.
    float*          part_conv = (float*)xb;
    float*          pn        = (float*)i2c;
    float*          pd        = pn + (size_t)256*4*64*64;
    unsigned short* outpre    = xb;

    // 1. all prep (x cvt + weight transposes + biases + conv_w cvt), 1 launch
    prep_all_kernel<<<37440, 256, 0, stream>>>(x, Wq, Wkv, proj_w, conv_w,
                                               an_bias, na_bias, ah_bias, aw_bias,
                                               ha_bias, wa_bias,
                                               xb, wqkvt, projwt, bias1, bias2, convwb);
    // 2. qkv = x @ [Wq|Wkv]  (M=32768, N=1536, K=512) -> bf16
    gemm_nt8<1><<<dim3(6, 128), 512, 0, stream>>>(xb, wqkvt, qkv, nullptr, 512, 1536);
    // 3. pool (r8-verified separate kernels: 4704 + 42336 blocks, full TLP)
    pool_kernel<<<4704, 256, 0, stream>>>(qkv, context, pooled);
    im2col_kernel<<<42336, 256, 0, stream>>>(pooled, i2c);
    // 4. conv as split-K GEMM (M=1568 pad 1664, N=512, K=6912, 9 slices of 768)
    gemm_nt<3><<<dim3(4, 13, 9), 256, 0, stream>>>(i2c, convwb, part_conv, nullptr, 6912, 512, 768);
    // 5. reduce partials -> bf16 a_t
    convred_kernel<<<784, 256, 0, stream>>>(part_conv, conv_b, at_bf);
    // 6. MFMA agent attention, 4 j-slices + combine (emits avT bf16)
    agent_attn_mfma_kernel<<<dim3(256, 4), 256, 0, stream>>>(qkv, at_bf, bias1, pn, pd);
    agent_combine_kernel<<<4096, 256, 0, stream>>>(pn, pd, avT);
    // 7. MFMA q-attention + fused dwc
    qattn_mfma_kernel<<<dim3(256, 4), 256, 0, stream>>>(qkv, at_bf, avT, bias2,
                                                        dwc_w, dwc_b, outpre);
    // 8. final: out_pre @ proj_w + proj_b  (M=32768, N=512, K=512) -> f32
    gemm_nt8<0><<<dim3(2, 128), 512, 0, stream>>>(outpre, projwt, d_out, proj_b, 512, 512);
}

// Round 11
// 451.180 us; speedup vs baseline: 1.2972x; 1.0425x over previous
//
#include <hip/hip_runtime.h>
#include <stdint.h>

// ---------------------------------------------------------------------------
// Problem constants (fixed by setup_inputs)
// b=32, n=1024, dim=512, ic=512, cc=256, nh=8, ag=49, hd=64, H=W=c_H=c_W=32
// ---------------------------------------------------------------------------

typedef __attribute__((ext_vector_type(8)))  short          bf16x8;
typedef __attribute__((ext_vector_type(4)))  float          f32x4;
typedef __attribute__((ext_vector_type(4)))  unsigned short u16x4;

__device__ __forceinline__ float bf2f(unsigned short u) {
    union { unsigned int i; float f; } x; x.i = ((unsigned int)u) << 16; return x.f;
}
__device__ __forceinline__ unsigned short f2bf(float f) {
    union { float f; unsigned int i; } x; x.f = f;
    unsigned int i = x.i;
    i += 0x7FFFu + ((i >> 16) & 1u);   // RNE
    return (unsigned short)(i >> 16);
}

// ---------------------------------------------------------------------------
// Bias precompute helpers (bilinear 7->32, clamp edges)
// ---------------------------------------------------------------------------
__device__ __forceinline__ void bilin_coef(int i, int& i0, int& i1, float& f) {
    float pos = (i + 0.5f) * (7.0f / 32.0f) - 0.5f;
    float fl = floorf(pos);
    i0 = (int)fl; f = pos - fl;
    if (i0 < 0)       { i0 = 0; i1 = 0; f = 0.f; }
    else if (i0 >= 6) { i0 = 6; i1 = 6; f = 0.f; }
    else              { i1 = i0 + 1; }
}
__device__ __forceinline__ float bilin7(const float* __restrict__ s, int y, int x) {
    int y0,y1,x0,x1; float fy,fx;
    bilin_coef(y, y0, y1, fy); bilin_coef(x, x0, x1, fx);
    return (1.f-fy)*((1.f-fx)*s[y0*7+x0] + fx*s[y0*7+x1])
         +      fy *((1.f-fx)*s[y1*7+x0] + fx*s[y1*7+x1]);
}

// ---------------------------------------------------------------------------
// Merged prep kernel (6-in-1, one launch; r10-verified).
// r11 change: convwb is now TAP-MAJOR: convwb[co*6912 + r*768 + ci] =
// conv_w[co][ci][r] — matches the im2col-free conv GEMM K-ordering.
// Ranges: [0,4194304) x cvt | wqkvt 786432 | projwt 262144
//         | bias1 401408 | bias2 401408 | convwb 3538944.
// ---------------------------------------------------------------------------
__global__ void prep_all_kernel(const float* __restrict__ x,
                                const float* __restrict__ Wq,
                                const float* __restrict__ Wkv,
                                const float* __restrict__ Wproj,
                                const float* __restrict__ conv_w,
                                const float* __restrict__ an, const float* __restrict__ na,
                                const float* __restrict__ ah, const float* __restrict__ aw,
                                const float* __restrict__ ha, const float* __restrict__ wa,
                                unsigned short* __restrict__ xb,
                                unsigned short* __restrict__ wqkvt,
                                unsigned short* __restrict__ projwt,
                                float* __restrict__ bias1,
                                float* __restrict__ bias2,
                                unsigned short* __restrict__ convwb) {
    int idx = blockIdx.x * 256 + threadIdx.x;
    if (idx < 4194304) {
        const int i = idx * 4;
        const f32x4 v = *(const f32x4*)(x + i);
        u16x4 o; o[0]=f2bf(v[0]); o[1]=f2bf(v[1]); o[2]=f2bf(v[2]); o[3]=f2bf(v[3]);
        *(u16x4*)(xb + i) = o;
        return;
    }
    idx -= 4194304;
    if (idx < 786432) {
        const int nn = idx >> 9, kk = idx & 511;
        float v = (nn < 512) ? Wq[kk*512 + nn] : Wkv[kk*1024 + (nn - 512)];
        wqkvt[idx] = f2bf(v);
        return;
    }
    idx -= 786432;
    if (idx < 262144) {
        const int nn = idx >> 9, kk = idx & 511;
        projwt[idx] = f2bf(Wproj[kk*512 + nn]);
        return;
    }
    idx -= 262144;
    if (idx < 8*49*1024) {
        const int nn = idx & 1023;
        const int a  = (idx >> 10) % 49;
        const int h  = idx / (49*1024);
        const int y = nn >> 5, xq = nn & 31;
        float v = bilin7(an + (h*49 + a)*49, y, xq)
                + ah[(h*49 + a)*32 + y] + aw[(h*49 + a)*32 + xq];
        bias1[idx] = v;
        return;
    }
    idx -= 8*49*1024;
    if (idx < 8*1024*49) {
        const int a  = idx % 49;
        const int nn = (idx / 49) & 1023;
        const int h  = idx / (49*1024);
        const int y = nn >> 5, xq = nn & 31;
        float v = bilin7(na + (h*49 + a)*49, y, xq)
                + ha[h*1568 + y*49 + a] + wa[h*1568 + xq*49 + a];
        bias2[idx] = v;
        return;
    }
    idx -= 8*1024*49;
    if (idx < 3538944) {
        const int co  = idx / 6912;
        const int rem = idx - co*6912;
        const int r   = rem / 768, ci = rem - r*768;
        convwb[idx] = f2bf(conv_w[((size_t)co*768 + ci)*9 + r]);
    }
}

// ---------------------------------------------------------------------------
// Adaptive avg-pool 32x32 -> 7x7, bf16 out with a ZERO GUARD ROW (a==49).
// Layout: pooledbf[b*38400 + a*768 + c], a in [0,50). Same window math and
// f2bf rounding as the old pool+im2col pair -> conv inputs bit-identical.
// 4800 blocks, full TLP (r9 lesson: never shrink this kernel's grid).
// ---------------------------------------------------------------------------
__global__ void pool_kernel(const unsigned short* __restrict__ qkv,
                            const float* __restrict__ context,
                            unsigned short* __restrict__ pooledbf) {
    const int idx = blockIdx.x * 256 + threadIdx.x;   // b*38400 + a*768 + c
    if (idx >= 32*50*768) return;
    const int c = idx % 768;
    const int a = (idx / 768) % 50;
    const int b = idx / (768*50);
    if (a >= 49) { pooledbf[idx] = 0; return; }       // guard row (conv border)
    const int p = a / 7, q = a % 7;
    const int ys = p*32/7, ye = (p*32 + 38)/7;
    const int xs = q*32/7, xe = (q*32 + 38)/7;
    float s = 0.f;
    if (c < 512) {
        for (int y = ys; y < ye; ++y)
            for (int x = xs; x < xe; ++x)
                s += bf2f(qkv[(size_t)(b*1024 + y*32 + x)*1536 + c]);
    } else {
        for (int y = ys; y < ye; ++y)
            for (int x = xs; x < xe; ++x)
                s += context[(size_t)(b*1024 + y*32 + x)*256 + (c - 512)];
    }
    pooledbf[idx] = f2bf(s / (float)((ye - ys)*(xe - xs)));
}

// ---------------------------------------------------------------------------
// im2col-FREE conv GEMM (r11). Split-K slice z == tap (dy,dx); kspan=768
// == one tap, so each slice is a plain GEMM over pooledbf with a per-row
// patch remap: A[m][z*768+ci] = pooledbf[b][shift(spq,z)][ci], border -> the
// zero guard row 49. global_load_lds source is per-lane, so the remap is
// free; 16B alignment preserved (768 & scol are x8-element aligned).
// Writes f32 partials to part[(z*1568 + m)*512 + n], mask m<1568.
// ---------------------------------------------------------------------------
__launch_bounds__(256)
__global__ void gemm_conv(const unsigned short* __restrict__ Ap,   // pooledbf
                          const unsigned short* __restrict__ Bt,   // convwb tap-major
                          float* __restrict__ part) {
    __shared__ __align__(16) unsigned char smem_raw[32768];
    unsigned short* As = (unsigned short*)smem_raw;           // [128][64] bf16
    unsigned short* Bs = (unsigned short*)(smem_raw + 16384); // [128][64] bf16

    // ---- T1 swizzle (grid 4 x 13 x 9 -> nwg=468) ----
    const int gx  = gridDim.x;
    const int gxy = gridDim.x * gridDim.y;
    const int nwg = gxy * gridDim.z;
    const int L   = (blockIdx.z * gridDim.y + blockIdx.y) * gx + blockIdx.x;
    const int qq  = nwg >> 3, rr = nwg & 7;
    const int xcd = L & 7,   ii = L >> 3;
    const int W   = (xcd < rr ? xcd * (qq + 1) : rr * (qq + 1) + (xcd - rr) * qq) + ii;
    const int bz  = W / gxy;
    const int rem = W - bz * gxy;
    const int by  = rem / gx;
    const int bx  = rem - by * gx;

    const int tid  = threadIdx.x;
    const int wid  = tid >> 6;
    const int lane = tid & 63;
    const int m0 = by * 128;
    const int n0 = bx * 128;
    const int wm = (wid >> 1) * 64;
    const int wn = (wid & 1) * 64;
    const int lrow = lane & 15;
    const int quad = lane >> 4;
    const int srow = lane >> 3;
    const int scol = ((lane & 7) ^ srow) * 8;
    const int dy0 = bz / 3 - 1;            // tap row offset  (-1..1)
    const int dx0 = bz - (bz / 3) * 3 - 1; // tap col offset  (-1..1)

    f32x4 acc[4][4];
#pragma unroll
    for (int i = 0; i < 4; ++i)
#pragma unroll
        for (int j = 0; j < 4; ++j) acc[i][j] = (f32x4){0.f,0.f,0.f,0.f};

    const int kz0 = bz * 768;
    for (int c0 = 0; c0 < 768; c0 += 64) {
        __syncthreads();
#pragma unroll
        for (int i = 0; i < 4; ++i) {
            const int chunk = wid*4 + i;
            const int row = chunk*8 + srow;
            const int gm  = m0 + row;                 // padded m (< 1664)
            const int bb  = gm / 49, spq = gm - bb*49;
            const int pr  = spq / 7;
            const int pp  = pr + dy0, qc = (spq - pr*7) + dx0;
            const int ridx = ((unsigned)pp < 7u && (unsigned)qc < 7u) ? pp*7 + qc : 49;
            __builtin_amdgcn_global_load_lds(
                (const __attribute__((address_space(1))) void*)
                    (Ap + ((size_t)bb*50 + ridx)*768 + c0 + scol),
                (__attribute__((address_space(3))) void*)(As + chunk*512), 16, 0, 0);
            __builtin_amdgcn_global_load_lds(
                (const __attribute__((address_space(1))) void*)
                    (Bt + (size_t)(n0 + row)*6912 + kz0 + c0 + scol),
                (__attribute__((address_space(3))) void*)(Bs + chunk*512), 16, 0, 0);
        }
        __syncthreads();
#pragma unroll
        for (int kk = 0; kk < 2; ++kk) {
            bf16x8 af[4], bfr[4];
#pragma unroll
            for (int mt = 0; mt < 4; ++mt) {
                const int row = wm + mt*16 + lrow;
                const int u = (kk*4 + quad) ^ (row & 7);
                af[mt] = *(const bf16x8*)(As + row*64 + u*8);
            }
#pragma unroll
            for (int nt = 0; nt < 4; ++nt) {
                const int row = wn + nt*16 + lrow;
                const int u = (kk*4 + quad) ^ (row & 7);
                bfr[nt] = *(const bf16x8*)(Bs + row*64 + u*8);
            }
#pragma unroll
            for (int mt = 0; mt < 4; ++mt)
#pragma unroll
                for (int nt = 0; nt < 4; ++nt)
                    acc[mt][nt] = __builtin_amdgcn_mfma_f32_16x16x32_bf16(
                        af[mt], bfr[nt], acc[mt][nt], 0, 0, 0);
        }
    }

    // ---- LDS-staged f32 epilogue (r10-verified) ----
    __syncthreads();
    {
        float* Cf = (float*)smem_raw;                     // [64][128] f32, XOR-swz
#pragma unroll
        for (int half = 0; half < 2; ++half) {
            if ((wid >> 1) == half) {
#pragma unroll
                for (int mt = 0; mt < 4; ++mt)
#pragma unroll
                    for (int nt = 0; nt < 4; ++nt)
#pragma unroll
                        for (int r = 0; r < 4; ++r) {
                            const int mr = mt*16 + quad*4 + r;
                            const int n  = wn + nt*16 + lrow;
                            Cf[mr*128 + (n ^ ((mr & 7) << 2))] = acc[mt][nt][r];
                        }
            }
            __syncthreads();
#pragma unroll
            for (int it = 0; it < 8; ++it) {
                const int idx = it*256 + tid;
                const int row = idx >> 5, c4 = idx & 31;
                const int m = m0 + half*64 + row;
                f32x4 v = *(const f32x4*)(Cf + row*128 + ((c4*4) ^ ((row & 7) << 2)));
                if (m < 1568)
                    *(f32x4*)(part + ((size_t)bz*1568 + m)*512 + n0 + c4*4) = v;
            }
            __syncthreads();
        }
    }
}

// ---------------------------------------------------------------------------
// 256x256 8-phase pipelined NT bf16 GEMM (T3+T4+T5+T2, verified r5).
// MODE 0: f32 C + bias (proj)    MODE 1: bf16 C (qkv)
// ---------------------------------------------------------------------------
#define STAGE_A(DST, T, Q) do {                                                             \
    _Pragma("unroll")                                                                       \
    for (int l_ = 0; l_ < 2; ++l_) {                                                        \
        const int rb_ = l_*128 + (Q)*64 + wid*8;                                            \
        __builtin_amdgcn_global_load_lds(                                                   \
            (const __attribute__((address_space(1))) void*)                                 \
                (Ag + (size_t)(m0 + rb_ + lr8)*K + (T)*64 + scl),                           \
            (__attribute__((address_space(3))) void*)((DST) + rb_*64), 16, 0, 0);           \
    }                                                                                       \
} while (0)

#define STAGE_B(DST, T, NH) do {                                                            \
    _Pragma("unroll")                                                                       \
    for (int l_ = 0; l_ < 2; ++l_) {                                                        \
        const int w8_ = wid*8;                                                              \
        const int rb_ = l_*128 + ((w8_ >> 5) << 6) + (NH)*32 + (w8_ & 31);                  \
        __builtin_amdgcn_global_load_lds(                                                   \
            (const __attribute__((address_space(1))) void*)                                 \
                (Btg + (size_t)(n0 + rb_ + lr8)*K + (T)*64 + scl),                          \
            (__attribute__((address_space(3))) void*)((DST) + rb_*64), 16, 0, 0);           \
    }                                                                                       \
} while (0)

#define LOAD_A(MH, SRC) do {                                                                \
    _Pragma("unroll")                                                                       \
    for (int m4_ = 0; m4_ < 4; ++m4_)                                                       \
    _Pragma("unroll")                                                                       \
    for (int kk_ = 0; kk_ < 2; ++kk_)                                                       \
        aF[m4_][kk_] = *(const bf16x8*)                                                     \
            ((SRC) + (wr*128 + ((MH)*4 + m4_)*16 + l15)*64                                  \
                   + (((kk_*4 + quad) ^ sw7) * 8));                                         \
} while (0)

#define LOAD_B(NH, DSTF, SRC) do {                                                          \
    _Pragma("unroll")                                                                       \
    for (int n2_ = 0; n2_ < 2; ++n2_)                                                       \
    _Pragma("unroll")                                                                       \
    for (int kk_ = 0; kk_ < 2; ++kk_)                                                       \
        DSTF[n2_][kk_] = *(const bf16x8*)                                                   \
            ((SRC) + (wc*64 + ((NH)*2 + n2_)*16 + l15)*64                                   \
                   + (((kk_*4 + quad) ^ sw7) * 8));                                         \
} while (0)

#define MFMA_PHASE(MH, NH, BF) do {                                                         \
    __builtin_amdgcn_s_barrier();                                                           \
    asm volatile("s_waitcnt lgkmcnt(0)");                                                   \
    __builtin_amdgcn_sched_barrier(0);                                                      \
    __builtin_amdgcn_s_setprio(1);                                                          \
    _Pragma("unroll")                                                                       \
    for (int kk_ = 0; kk_ < 2; ++kk_)                                                       \
    _Pragma("unroll")                                                                       \
    for (int m4_ = 0; m4_ < 4; ++m4_)                                                       \
    _Pragma("unroll")                                                                       \
    for (int n2_ = 0; n2_ < 2; ++n2_)                                                       \
        acc[(MH)*4 + m4_][(NH)*2 + n2_] = __builtin_amdgcn_mfma_f32_16x16x32_bf16(          \
            aF[m4_][kk_], BF[n2_][kk_], acc[(MH)*4 + m4_][(NH)*2 + n2_], 0, 0, 0);          \
    __builtin_amdgcn_s_setprio(0);                                                          \
    __builtin_amdgcn_sched_barrier(0);                                                      \
} while (0)

template <int MODE>
__launch_bounds__(512, 1)
__global__ void gemm_nt8(const unsigned short* __restrict__ Ag,
                         const unsigned short* __restrict__ Btg,
                         void* __restrict__ C,
                         const float* __restrict__ bias,
                         int K, int ldc) {
    __shared__ unsigned short AsB[2][16384];
    __shared__ unsigned short BsB[2][16384];

    const int gx  = gridDim.x;
    const int nwg = gx * gridDim.y;
    const int L   = blockIdx.y * gx + blockIdx.x;
    const int qq  = nwg >> 3, rr = nwg & 7;
    const int xcd = L & 7,   ii = L >> 3;
    const int W   = (xcd < rr ? xcd * (qq + 1) : rr * (qq + 1) + (xcd - rr) * qq) + ii;
    const int bx  = W % gx, by = W / gx;
    const int m0  = by * 256, n0 = bx * 256;

    const int tid  = threadIdx.x;
    const int wid  = tid >> 6, lane = tid & 63;
    const int wr   = wid >> 2, wc = wid & 3;
    const int l15  = lane & 15, quad = lane >> 4;
    const int lr8  = lane >> 3;
    const int scl  = ((lane & 7) ^ lr8) * 8;
    const int sw7  = l15 & 7;
    const int KT   = K >> 6;

    unsigned short *Acur = &AsB[0][0], *Anxt = &AsB[1][0];
    unsigned short *Bcur = &BsB[0][0], *Bnxt = &BsB[1][0];

    f32x4 acc[8][4];
#pragma unroll
    for (int i = 0; i < 8; ++i)
#pragma unroll
        for (int j = 0; j < 4; ++j) acc[i][j] = (f32x4){0.f,0.f,0.f,0.f};

    bf16x8 aF[4][2], bF0[2][2], bF1[2][2];

    STAGE_A(Acur, 0, 0); STAGE_B(Bcur, 0, 1); STAGE_A(Acur, 0, 1); STAGE_B(Bcur, 0, 0);
    STAGE_A(Anxt, 1, 0); STAGE_B(Bnxt, 1, 1); STAGE_A(Anxt, 1, 1);
    asm volatile("s_waitcnt vmcnt(6)");
    __builtin_amdgcn_s_barrier();

    for (int t = 0; t < KT; ++t) {
        LOAD_B(0, bF0, Bcur);
        LOAD_A(0, Acur);
        if (t + 1 < KT) STAGE_B(Bnxt, t + 1, 0);
        MFMA_PHASE(0, 0, bF0);
        __builtin_amdgcn_s_barrier();

        LOAD_B(1, bF1, Bcur);
        if (t + 2 < KT) STAGE_A(Acur, t + 2, 0);
        MFMA_PHASE(0, 1, bF1);
        __builtin_amdgcn_s_barrier();

        LOAD_A(1, Acur);
        if (t + 2 < KT) STAGE_B(Bcur, t + 2, 1);
        MFMA_PHASE(1, 1, bF1);
        __builtin_amdgcn_s_barrier();

        LOAD_B(0, bF0, Bcur);
        if (t + 2 < KT) STAGE_A(Acur, t + 2, 1);
        MFMA_PHASE(1, 0, bF0);
        if (t + 2 < KT) asm volatile("s_waitcnt vmcnt(6)");
        else            asm volatile("s_waitcnt vmcnt(0)");
        __builtin_amdgcn_s_barrier();

        unsigned short* tmp;
        tmp = Acur; Acur = Anxt; Anxt = tmp;
        tmp = Bcur; Bcur = Bnxt; Bnxt = tmp;
    }

    if (MODE == 1) {
#pragma unroll
        for (int mt = 0; mt < 8; ++mt)
#pragma unroll
            for (int nt = 0; nt < 4; ++nt)
#pragma unroll
                for (int r = 0; r < 4; ++r) {
                    const int m = m0 + wr*128 + mt*16 + quad*4 + r;
                    const int n = n0 + wc*64  + nt*16 + l15;
                    ((unsigned short*)C)[(size_t)m*ldc + n] = f2bf(acc[mt][nt][r]);
                }
    } else {
        float bv[4];
#pragma unroll
        for (int nt = 0; nt < 4; ++nt) bv[nt] = bias[n0 + wc*64 + nt*16 + l15];
#pragma unroll
        for (int mt = 0; mt < 8; ++mt)
#pragma unroll
            for (int nt = 0; nt < 4; ++nt)
#pragma unroll
                for (int r = 0; r < 4; ++r) {
                    const int m = m0 + wr*128 + mt*16 + quad*4 + r;
                    const int n = n0 + wc*64  + nt*16 + l15;
                    ((float*)C)[(size_t)m*ldc + n] = acc[mt][nt][r] + bv[nt];
                }
    }
}

#undef STAGE_A
#undef STAGE_B
#undef LOAD_A
#undef LOAD_B
#undef MFMA_PHASE

// Sum 9 split-K partials, add conv bias, emit bf16 a_t.
__global__ void convred_kernel(const float* __restrict__ part,
                               const float* __restrict__ bias,
                               unsigned short* __restrict__ at_bf) {
    const int idx = blockIdx.x * 256 + threadIdx.x;   // over 1568*128
    if (idx >= 1568*128) return;
    const int m  = idx >> 7;
    const int n4 = (idx & 127) * 4;
    f32x4 s = *(const f32x4*)&part[(size_t)m*512 + n4];
#pragma unroll
    for (int kz = 1; kz < 9; ++kz) {
        const f32x4 p = *(const f32x4*)&part[((size_t)kz*1568 + m)*512 + n4];
        s[0]+=p[0]; s[1]+=p[1]; s[2]+=p[2]; s[3]+=p[3];
    }
    u16x4 o;
    o[0] = f2bf(s[0] + bias[n4+0]);
    o[1] = f2bf(s[1] + bias[n4+1]);
    o[2] = f2bf(s[2] + bias[n4+2]);
    o[3] = f2bf(s[3] + bias[n4+3]);
    *(u16x4*)&at_bf[(size_t)m*512 + n4] = o;
}

// ---------------------------------------------------------------------------
// MFMA agent attention. Grid (256 bh, 4 slices), 256 thr (4 waves).
// ---------------------------------------------------------------------------
__launch_bounds__(256)
__global__ void agent_attn_mfma_kernel(const unsigned short* __restrict__ qkv,
                                       const unsigned short* __restrict__ at_bf,
                                       const float* __restrict__ bias1,
                                       float* __restrict__ pn,
                                       float* __restrict__ pd) {
    const int bh = blockIdx.x;
    const int b = bh >> 3, h = bh & 7;
    const int sl = blockIdx.y;
    __shared__ unsigned short at_s[64*72];
    __shared__ __align__(16) unsigned char smem[4*64*72*2 + 4*64*64*2];
    unsigned short* P_s = (unsigned short*)smem;
    unsigned short* V_s = (unsigned short*)(smem + 36864);
    float* red  = (float*)smem;
    float* dred = (float*)(smem + 65536);
    const int tid  = threadIdx.x;
    const int wid  = tid >> 6, lane = tid & 63;
    const int l15  = lane & 15, quad = lane >> 4;
    const int j0   = sl*256 + wid*64;

    for (int i = tid; i < 64*72; i += 256) at_s[i] = 0;
    __syncthreads();
    for (int i = tid; i < 49*16; i += 256) {
        const int a = i >> 4, dq = (i & 15) * 4;
        *(u16x4*)&at_s[a*72 + dq] = *(const u16x4*)&at_bf[(size_t)(b*49 + a)*512 + h*64 + dq];
    }
#pragma unroll
    for (int i = 0; i < 8; ++i) {
        __builtin_amdgcn_global_load_lds(
            (const __attribute__((address_space(1))) void*)
                (qkv + (size_t)(b*1024 + j0 + i*8 + (lane>>3))*1536 + 1024 + h*64 + (lane&7)*8),
            (__attribute__((address_space(3))) void*)(V_s + wid*4096 + i*512), 16, 0, 0);
    }
    bf16x8 kfr[4][2];
#pragma unroll
    for (int nt = 0; nt < 4; ++nt)
#pragma unroll
        for (int kf = 0; kf < 2; ++kf)
            kfr[nt][kf] = *(const bf16x8*)
                (qkv + (size_t)(b*1024 + j0 + nt*16 + l15)*1536 + 512 + h*64 + kf*32 + quad*8);
    __syncthreads();

    bf16x8 af[4][2];
#pragma unroll
    for (int mt = 0; mt < 4; ++mt)
#pragma unroll
        for (int kf = 0; kf < 2; ++kf)
            af[mt][kf] = *(const bf16x8*)(at_s + (mt*16 + l15)*72 + kf*32 + quad*8);

    f32x4 acc[4][4];
#pragma unroll
    for (int i = 0; i < 4; ++i)
#pragma unroll
        for (int j = 0; j < 4; ++j) acc[i][j] = (f32x4){0.f,0.f,0.f,0.f};
#pragma unroll
    for (int kf = 0; kf < 2; ++kf)
#pragma unroll
        for (int mt = 0; mt < 4; ++mt)
#pragma unroll
            for (int nt = 0; nt < 4; ++nt)
                acc[mt][nt] = __builtin_amdgcn_mfma_f32_16x16x32_bf16(
                    af[mt][kf], kfr[nt][kf], acc[mt][nt], 0, 0, 0);

    float denp[4][4];
#pragma unroll
    for (int mt = 0; mt < 4; ++mt)
#pragma unroll
        for (int r = 0; r < 4; ++r) denp[mt][r] = 0.f;
#pragma unroll
    for (int mt = 0; mt < 4; ++mt) {
#pragma unroll
        for (int nt = 0; nt < 4; ++nt) {
#pragma unroll
            for (int r = 0; r < 4; ++r) {
                const int a  = mt*16 + quad*4 + r;
                const int ab = (a < 49) ? a : 48;
                const int jj = j0 + nt*16 + l15;
                const float e = __expf(fmaf(0.125f, acc[mt][nt][r],
                                            bias1[(h*49 + ab)*1024 + jj]));
                denp[mt][r] += e;
                P_s[wid*4608 + a*72 + nt*16 + l15] = f2bf(e);
            }
        }
    }
    __syncthreads();

    f32x4 out[4][4];
#pragma unroll
    for (int i = 0; i < 4; ++i)
#pragma unroll
        for (int j = 0; j < 4; ++j) out[i][j] = (f32x4){0.f,0.f,0.f,0.f};
#pragma unroll
    for (int kf = 0; kf < 2; ++kf) {
        bf16x8 va[4];
#pragma unroll
        for (int mt = 0; mt < 4; ++mt) {
            union { bf16x8 v; unsigned short s[8]; } u;
#pragma unroll
            for (int t = 0; t < 8; ++t)
                u.s[t] = V_s[wid*4096 + (kf*32 + quad*8 + t)*64 + mt*16 + l15];
            va[mt] = u.v;
        }
#pragma unroll
        for (int nt = 0; nt < 4; ++nt) {
            const bf16x8 pb = *(const bf16x8*)(P_s + wid*4608 + (nt*16 + l15)*72 + kf*32 + quad*8);
#pragma unroll
            for (int mt = 0; mt < 4; ++mt)
                out[mt][nt] = __builtin_amdgcn_mfma_f32_16x16x32_bf16(
                    va[mt], pb, out[mt][nt], 0, 0, 0);
        }
    }

#pragma unroll
    for (int mt = 0; mt < 4; ++mt) {
#pragma unroll
        for (int r = 0; r < 4; ++r) {
            float v = denp[mt][r];
            v += __shfl_xor(v, 1);
            v += __shfl_xor(v, 2);
            v += __shfl_xor(v, 4);
            v += __shfl_xor(v, 8);
            denp[mt][r] = v;
        }
    }

    __syncthreads();
#pragma unroll
    for (int nt = 0; nt < 4; ++nt) {
        const int a = nt*16 + l15;
#pragma unroll
        for (int mt = 0; mt < 4; ++mt)
            *(f32x4*)&red[wid*4096 + a*64 + mt*16 + quad*4] = out[mt][nt];
    }
    if (l15 == 0) {
#pragma unroll
        for (int mt = 0; mt < 4; ++mt)
#pragma unroll
            for (int r = 0; r < 4; ++r)
                dred[wid*64 + mt*16 + quad*4 + r] = denp[mt][r];
    }
    __syncthreads();
    for (int i = tid; i < 4096; i += 256) {
        const float s = red[i] + red[4096 + i] + red[8192 + i] + red[12288 + i];
        pn[((size_t)bh*4 + sl)*4096 + i] = s;
    }
    if (tid < 64) {
        const float s = dred[tid] + dred[64 + tid] + dred[128 + tid] + dred[192 + tid];
        pd[((size_t)bh*4 + sl)*64 + tid] = s;
    }
}

// Combine 4 j-slice partials; emit bf16 agent_v transposed [bh][d][a-pad-64].
__global__ void agent_combine_kernel(const float* __restrict__ pn,
                                     const float* __restrict__ pd,
                                     unsigned short* __restrict__ avT) {
    const int idx = blockIdx.x * 256 + threadIdx.x;
    if (idx >= 256*4096) return;
    const int bh = idx >> 12;
    const int i  = idx & 4095;
    const int a = i >> 6, d = i & 63;
    float num = 0.f, den = 0.f;
#pragma unroll
    for (int s = 0; s < 4; ++s) {
        num += pn[(((size_t)bh*4 + s)*64 + a)*64 + d];
        den += pd[((size_t)bh*4 + s)*64 + a];
    }
    avT[(size_t)bh*4096 + d*64 + a] = (a < 49) ? f2bf(num / den) : (unsigned short)0;
}

// ---------------------------------------------------------------------------
// MFMA q-attention + fused depthwise conv (r8 LDS-diet version: 36.9 KB
// union, out_s [128][66] two half-passes, 4 blocks/CU).
// ---------------------------------------------------------------------------
__launch_bounds__(256)
__global__ void qattn_mfma_kernel(const unsigned short* __restrict__ qkv,
                                  const unsigned short* __restrict__ at_bf,
                                  const unsigned short* __restrict__ avT,
                                  const float* __restrict__ bias2,
                                  const float* __restrict__ dwc_w,
                                  const float* __restrict__ dwc_b,
                                  unsigned short* __restrict__ out_pre) {
    const int bh = blockIdx.x;
    const int b = bh >> 3, h = bh & 7;
    const int tq = blockIdx.y;
    __shared__ __align__(16) unsigned char smem[36864];   // P_s / out_s union
    unsigned short* P_s = (unsigned short*)smem;   // [4][64*72] bf16 (phase A)
    float* out_s = (float*)smem;                   // [128][66] f32  (phase B)
    __shared__ float dwcw_s[64*9];
    __shared__ float dwcb_s[64];
    const int tid = threadIdx.x;
    const int wid = tid >> 6, lane = tid & 63;
    const int l15 = lane & 15, quad = lane >> 4;
    const int j0  = tq*256 + wid*64;

    for (int i = tid; i < 64*9; i += 256) dwcw_s[i] = dwc_w[h*576 + i];
    if (tid < 64) dwcb_s[tid] = dwc_b[h*64 + tid];

    bf16x8 qa[4][2];
#pragma unroll
    for (int mt = 0; mt < 4; ++mt)
#pragma unroll
        for (int kf = 0; kf < 2; ++kf)
            qa[mt][kf] = *(const bf16x8*)
                (qkv + (size_t)(b*1024 + j0 + mt*16 + l15)*1536 + h*64 + kf*32 + quad*8);
    bf16x8 ab[4][2];
#pragma unroll
    for (int nt = 0; nt < 4; ++nt) {
        const int a  = nt*16 + l15;
        const int ar = (a < 49) ? a : 48;
#pragma unroll
        for (int kf = 0; kf < 2; ++kf)
            ab[nt][kf] = *(const bf16x8*)
                (at_bf + (size_t)(b*49 + ar)*512 + h*64 + kf*32 + quad*8);
    }

    f32x4 e[4][4];
#pragma unroll
    for (int i = 0; i < 4; ++i)
#pragma unroll
        for (int j = 0; j < 4; ++j) e[i][j] = (f32x4){0.f,0.f,0.f,0.f};
#pragma unroll
    for (int kf = 0; kf < 2; ++kf)
#pragma unroll
        for (int mt = 0; mt < 4; ++mt)
#pragma unroll
            for (int nt = 0; nt < 4; ++nt)
                e[mt][nt] = __builtin_amdgcn_mfma_f32_16x16x32_bf16(
                    qa[mt][kf], ab[nt][kf], e[mt][nt], 0, 0, 0);

    float denp[4][4];
#pragma unroll
    for (int mt = 0; mt < 4; ++mt)
#pragma unroll
        for (int r = 0; r < 4; ++r) denp[mt][r] = 0.f;
#pragma unroll
    for (int mt = 0; mt < 4; ++mt) {
#pragma unroll
        for (int nt = 0; nt < 4; ++nt) {
            const int a = nt*16 + l15;
#pragma unroll
            for (int r = 0; r < 4; ++r) {
                if (a < 49) {
                    const int jj = j0 + mt*16 + quad*4 + r;
                    const float v = __expf(fmaf(0.125f, e[mt][nt][r],
                                                bias2[((size_t)h*1024 + jj)*49 + a]));
                    e[mt][nt][r] = v;
                    denp[mt][r] += v;
                } else {
                    e[mt][nt][r] = 0.f;
                }
            }
        }
    }
#pragma unroll
    for (int mt = 0; mt < 4; ++mt) {
#pragma unroll
        for (int r = 0; r < 4; ++r) {
            float v = denp[mt][r];
            v += __shfl_xor(v, 1);
            v += __shfl_xor(v, 2);
            v += __shfl_xor(v, 4);
            v += __shfl_xor(v, 8);
            denp[mt][r] = 1.0f / v;
        }
    }
#pragma unroll
    for (int mt = 0; mt < 4; ++mt)
#pragma unroll
        for (int nt = 0; nt < 4; ++nt)
#pragma unroll
            for (int r = 0; r < 4; ++r)
                P_s[wid*4608 + (mt*16 + quad*4 + r)*72 + nt*16 + l15] =
                    f2bf(e[mt][nt][r] * denp[mt][r]);

    bf16x8 bv[4][2];
#pragma unroll
    for (int nt = 0; nt < 4; ++nt)
#pragma unroll
        for (int kf = 0; kf < 2; ++kf)
            bv[nt][kf] = *(const bf16x8*)
                (avT + (size_t)bh*4096 + (nt*16 + l15)*64 + kf*32 + quad*8);
    f32x4 out[4][4];
#pragma unroll
    for (int i = 0; i < 4; ++i)
#pragma unroll
        for (int j = 0; j < 4; ++j) out[i][j] = (f32x4){0.f,0.f,0.f,0.f};
#pragma unroll
    for (int kf = 0; kf < 2; ++kf) {
        bf16x8 pa[4];
#pragma unroll
        for (int mt = 0; mt < 4; ++mt)
            pa[mt] = *(const bf16x8*)(P_s + wid*4608 + (mt*16 + l15)*72 + kf*32 + quad*8);
#pragma unroll
        for (int nt = 0; nt < 4; ++nt)
#pragma unroll
            for (int mt = 0; mt < 4; ++mt)
                out[mt][nt] = __builtin_amdgcn_mfma_f32_16x16x32_bf16(
                    pa[mt], bv[nt][kf], out[mt][nt], 0, 0, 0);
    }

    __syncthreads();   // all waves done with P_s; re-carve smem as out_s

    const int tt = tid >> 2;
    const int p  = tid & 3;
    const int d0 = p*16;
#pragma unroll
    for (int pass = 0; pass < 2; ++pass) {
        if ((wid >> 1) == pass) {
#pragma unroll
            for (int mt = 0; mt < 4; ++mt)
#pragma unroll
                for (int nt = 0; nt < 4; ++nt)
#pragma unroll
                    for (int r = 0; r < 4; ++r)
                        out_s[((wid & 1)*64 + mt*16 + quad*4 + r)*66 + nt*16 + l15]
                            = out[mt][nt][r];
        }
        __syncthreads();
        for (int it = 0; it < 2; ++it) {
            const int tl = it*64 + tt;               // 0..127 (local row)
            const int jj = tq*256 + pass*128 + tl;   // global token
            float o[16];
#pragma unroll
            for (int i = 0; i < 16; ++i) o[i] = out_s[tl*66 + d0 + i] + dwcb_s[d0 + i];
            const int y = jj >> 5, x = jj & 31;
#pragma unroll
            for (int dy = 0; dy < 3; ++dy) {
                const int yy = y + dy - 1;
                if (yy < 0 || yy > 31) continue;
#pragma unroll
                for (int dx = 0; dx < 3; ++dx) {
                    const int xx = x + dx - 1;
                    if (xx < 0 || xx > 31) continue;
                    const unsigned short* vp =
                        qkv + (size_t)(b*1024 + yy*32 + xx)*1536 + 1024 + h*64 + d0;
#pragma unroll
                    for (int i4 = 0; i4 < 4; ++i4) {
                        const u16x4 v4 = *(const u16x4*)(vp + i4*4);
#pragma unroll
                        for (int i = 0; i < 4; ++i)
                            o[i4*4+i] = fmaf(dwcw_s[(d0 + i4*4 + i)*9 + dy*3 + dx],
                                             bf2f(v4[i]), o[i4*4+i]);
                    }
                }
            }
            unsigned short* op = out_pre + (size_t)(b*1024 + jj)*512 + h*64 + d0;
#pragma unroll
            for (int i4 = 0; i4 < 4; ++i4) {
                u16x4 w;
                w[0]=f2bf(o[i4*4+0]); w[1]=f2bf(o[i4*4+1]);
                w[2]=f2bf(o[i4*4+2]); w[3]=f2bf(o[i4*4+3]);
                *(u16x4*)(op + i4*4) = w;
            }
        }
        __syncthreads();
    }
}

// ---------------------------------------------------------------------------
extern "C" void kernel_launch(void* const* d_in, const int* in_sizes, int n_in,
                              void* d_out, int out_size, void* d_ws, size_t ws_size,
                              hipStream_t stream) {
    (void)in_sizes; (void)n_in; (void)out_size; (void)ws_size;
    const float* x       = (const float*)d_in[0];
    const float* context = (const float*)d_in[1];
    const float* Wq      = (const float*)d_in[2];
    const float* Wkv     = (const float*)d_in[3];
    const float* conv_w  = (const float*)d_in[4];
    const float* conv_b  = (const float*)d_in[5];
    const float* dwc_w   = (const float*)d_in[6];
    const float* dwc_b   = (const float*)d_in[7];
    const float* proj_w  = (const float*)d_in[8];
    const float* proj_b  = (const float*)d_in[9];
    const float* an_bias = (const float*)d_in[10];
    const float* na_bias = (const float*)d_in[11];
    const float* ah_bias = (const float*)d_in[12];
    const float* aw_bias = (const float*)d_in[13];
    const float* ha_bias = (const float*)d_in[14];
    const float* wa_bias = (const float*)d_in[15];

    char* ws = (char*)d_ws;
    size_t off = 0;
    auto alloc = [&](size_t bytes) -> char* {
        char* p = ws + off; off += (bytes + 255) & ~(size_t)255; return p;
    };
    unsigned short* xb     = (unsigned short*)alloc((size_t)16777216 * 2); // 33.5 MB
    unsigned short* qkv    = (unsigned short*)alloc((size_t)50331648 * 2);
    unsigned short* wqkvt  = (unsigned short*)alloc((size_t)786432  * 2);
    unsigned short* projwt = (unsigned short*)alloc((size_t)262144  * 2);
    unsigned short* convwb = (unsigned short*)alloc((size_t)3538944 * 2);
    unsigned short* pooledbf = (unsigned short*)alloc((size_t)34*50*768 * 2); // 2.6 MB (padded)
    unsigned short* at_bf  = (unsigned short*)alloc((size_t)1568*512*2);
    float*          bias1  = (float*)alloc((size_t)401408 * 4);
    float*          bias2  = (float*)alloc((size_t)401408 * 4);
    unsigned short* avT    = (unsigned short*)alloc((size_t)256*4096*2);
    float*          pn     = (float*)alloc((size_t)256*4*4096 * 4);        // 16.8 MB
    float*          pd     = (float*)alloc((size_t)256*4*64 * 4);
    // Aliases (stream-order safe): conv partials + outpre reuse xb after the
    // qkv GEMM finishes reading it (partials dead after convred; outpre
    // written later by qattn).
    float*          part_conv = (float*)xb;
    unsigned short* outpre    = xb;

    // 1. all prep (x cvt + weight transposes + biases + tap-major conv_w)
    prep_all_kernel<<<37440, 256, 0, stream>>>(x, Wq, Wkv, proj_w, conv_w,
                                               an_bias, na_bias, ah_bias, aw_bias,
                                               ha_bias, wa_bias,
                                               xb, wqkvt, projwt, bias1, bias2, convwb);
    // 2. qkv = x @ [Wq|Wkv]  (M=32768, N=1536, K=512) -> bf16
    gemm_nt8<1><<<dim3(6, 128), 512, 0, stream>>>(xb, wqkvt, qkv, nullptr, 512, 1536);
    // 3. pool -> bf16 with zero guard row (im2col eliminated entirely)
    pool_kernel<<<4800, 256, 0, stream>>>(qkv, context, pooledbf);
    // 4. im2col-free conv GEMM (split-K: z == tap, kspan=768)
    gemm_conv<<<dim3(4, 13, 9), 256, 0, stream>>>(pooledbf, convwb, part_conv);
    // 5. reduce partials -> bf16 a_t
    convred_kernel<<<784, 256, 0, stream>>>(part_conv, conv_b, at_bf);
    // 6. MFMA agent attention, 4 j-slices + combine (emits avT bf16)
    agent_attn_mfma_kernel<<<dim3(256, 4), 256, 0, stream>>>(qkv, at_bf, bias1, pn, pd);
    agent_combine_kernel<<<4096, 256, 0, stream>>>(pn, pd, avT);
    // 7. MFMA q-attention + fused dwc
    qattn_mfma_kernel<<<dim3(256, 4), 256, 0, stream>>>(qkv, at_bf, avT, bias2,
                                                        dwc_w, dwc_b, outpre);
    // 8. final: out_pre @ proj_w + proj_b  (M=32768, N=512, K=512) -> f32
    gemm_nt8<0><<<dim3(2, 128), 512, 0, stream>>>(outpre, projwt, d_out, proj_b, 512, 512);
}